// Round 1
// baseline (785.823 us; speedup 1.0000x reference)
//
#include <hip/hip_runtime.h>
#include <hip/hip_bf16.h>
#include <math.h>

#define BD   768
#define HH   192
#define NB   8
#define NLQ  64
#define NNC  2048
#define NNE  1200
#define M_ROWS (NB*NNC)   // 16384

typedef float  f32x4  __attribute__((ext_vector_type(4)));
typedef short  bf16x8 __attribute__((ext_vector_type(8)));

__device__ __forceinline__ float wave_sum64(float v){
  #pragma unroll
  for (int off = 32; off; off >>= 1) v += __shfl_xor(v, off);
  return v;
}
__device__ __forceinline__ unsigned short f2bf(float f){
  union { float f; unsigned int u; } v; v.f = f;
  unsigned int u = v.u + 0x7fffu + ((v.u >> 16) & 1u);   // RNE
  return (unsigned short)(u >> 16);
}
__device__ __forceinline__ float bf2f(unsigned short h){
  union { unsigned int u; float f; } v; v.u = ((unsigned int)h) << 16; return v.f;
}
__device__ __forceinline__ unsigned int pack2(float lo, float hi){
  return ((unsigned int)f2bf(hi) << 16) | (unsigned int)f2bf(lo);
}

// ======== coalesced tiled transpose+convert: dst[C][R] = bf16(src[R][C]) ====
__global__ __launch_bounds__(256)
void k_tcvt(const float* __restrict__ src, unsigned short* __restrict__ dst,
            int R, int C){
  __shared__ float T[32][33];
  const int tx = threadIdx.x & 31, ty = threadIdx.x >> 5;   // ty 0..7
  const int c0 = blockIdx.x * 32, r0 = blockIdx.y * 32;
  #pragma unroll
  for (int i = 0; i < 4; ++i)
    T[ty + i * 8][tx] = src[(size_t)(r0 + ty + i * 8) * C + c0 + tx];
  __syncthreads();
  #pragma unroll
  for (int i = 0; i < 4; ++i)
    dst[(size_t)(c0 + ty + i * 8) * R + r0 + tx] = f2bf(T[tx][ty + i * 8]);
}

// ======== dist_contrib[4][768] = dist_table @ W_ce[768:,:] + b_ce ========
__global__ __launch_bounds__(256)
void k_distc(const float* __restrict__ dtab, const float* __restrict__ W_ce,
             const float* __restrict__ b_ce, float* __restrict__ dcon){
  const int c = blockIdx.x * 256 + threadIdx.x;    // < 768
  float a0 = b_ce[c], a1 = a0, a2 = a0, a3 = a0;
  for (int d = 0; d < BD; ++d) {
    float w = W_ce[(size_t)(BD + d) * BD + c];
    a0 += dtab[d]          * w;
    a1 += dtab[BD + d]     * w;
    a2 += dtab[2 * BD + d] * w;
    a3 += dtab[3 * BD + d] * w;
  }
  dcon[c] = a0; dcon[BD + c] = a1; dcon[2 * BD + c] = a2; dcon[3 * BD + c] = a3;
}

// ======== A_c[row] = bf16(ctab[cid])  (concept half only) ========
__global__ __launch_bounds__(256)
void k_cvt_gather(const int* __restrict__ cids,
                  const float* __restrict__ ctab,
                  unsigned short* __restrict__ Ac){
  int idx = blockIdx.x * 256 + threadIdx.x;        // < 16384*96
  int row = idx / 96, kc = (idx - row * 96) * 8;
  int cid = cids[row];
  const float* src = ctab + (size_t)cid * BD + kc;
  float4 f0 = ((const float4*)src)[0];
  float4 f1 = ((const float4*)src)[1];
  uint4 o;
  o.x = pack2(f0.x, f0.y); o.y = pack2(f0.z, f0.w);
  o.z = pack2(f1.x, f1.y); o.w = pack2(f1.z, f1.w);
  *(uint4*)(Ac + (size_t)row * BD + kc) = o;
}

// ======== q_emb max-pool (y=0) + mdot (y=1) ========
__global__ __launch_bounds__(256)
void k_qemb(const float* __restrict__ qh, const float* __restrict__ w_mem1,
            float* __restrict__ qe, float* __restrict__ mdot){
  const int b = blockIdx.x, t = threadIdx.x;
  if (blockIdx.y == 1) {
    if (t < NLQ) {
      const float* q = qh + ((size_t)b * NLQ + t) * BD;
      float acc = 0.f;
      #pragma unroll 4
      for (int d = 0; d < BD; d += 4) {
        float4 v = *(const float4*)(q + d);
        acc += v.x*w_mem1[d] + v.y*w_mem1[d+1] + v.z*w_mem1[d+2] + v.w*w_mem1[d+3];
      }
      mdot[b * NLQ + t] = acc;
    }
    return;
  }
  for (int d = t; d < BD; d += 256) {
    const float* p = qh + (size_t)b * NLQ * BD + d;
    float m = -1e30f;
    for (int l = 0; l < NLQ; ++l) m = fmaxf(m, p[(size_t)l * BD]);
    qe[b * BD + d] = m;
  }
}

// ======== c_query/t_query for ALL batches: W read once ========
// thread owns one output column j, 8 batch accumulators; qe staged in LDS.
__global__ __launch_bounds__(256)
void k_query(const float* __restrict__ qe,
             const float* __restrict__ W_cs, const float* __restrict__ b_cs,
             const float* __restrict__ W_ts, const float* __restrict__ b_ts,
             float* __restrict__ c_query, float* __restrict__ t_query){
  __shared__ float qs[NB * BD];                    // 24 KB
  const int t = threadIdx.x;
  for (int i = t; i < NB * BD; i += 256) qs[i] = qe[i];
  __syncthreads();
  const int j = blockIdx.x * 256 + t;              // < 5376
  float acc[NB];
  if (j < 1536) {
    #pragma unroll
    for (int b = 0; b < NB; ++b) acc[b] = b_cs[j];
    for (int d = 0; d < BD; ++d) {
      float w = W_cs[(size_t)d * 1536 + j];
      #pragma unroll
      for (int b = 0; b < NB; ++b) acc[b] += qs[b * BD + d] * w;
    }
    #pragma unroll
    for (int b = 0; b < NB; ++b) c_query[b * 1536 + j] = acc[b];
  } else {
    const int j2 = j - 1536;
    #pragma unroll
    for (int b = 0; b < NB; ++b) acc[b] = b_ts[j2];
    for (int d = 0; d < BD; ++d) {
      float w = W_ts[(size_t)d * 3840 + j2];
      #pragma unroll
      for (int b = 0; b < NB; ++b) acc[b] += qs[b * BD + d] * w;
    }
    #pragma unroll
    for (int b = 0; b < NB; ++b) t_query[b * 3840 + j2] = acc[b];
  }
}

// ======== mem2t[b][h][l] = bf16(qh@W_mem2 + b)  +  qhx conversion ========
__global__ __launch_bounds__(256)
void k_mem2qhx(const float* __restrict__ qh, const float* __restrict__ W_mem2,
               const float* __restrict__ b_mem2, const float* __restrict__ w_in1,
               unsigned short* __restrict__ mem2t, unsigned short* __restrict__ qhx){
  int idx = blockIdx.x * 256 + threadIdx.x;        // < 98304 + 491520
  if (idx < 98304) {
    int h = idx % HH, bl = idx / HH;               // bl = b*64 + l
    int b = bl >> 6, l = bl & 63;
    const float* q = qh + (size_t)bl * BD;
    float acc = b_mem2[h];
    for (int d = 0; d < BD; ++d) acc += q[d] * W_mem2[(size_t)d * HH + h];
    mem2t[((size_t)b * HH + h) * 64 + l] = f2bf(acc);
  } else {
    int i = idx - 98304;
    int b = i / 61440, rk = i - b * 61440;
    int r = rk / BD, k = rk - r * BD;
    unsigned short v;
    if (r < 64)       v = f2bf(qh[((size_t)b * NLQ + r) * BD + k]);
    else if (r == 64) v = f2bf(w_in1[k] * 27.712812921102035f);  // sqrt(768)
    else              v = 0;
    qhx[i] = v;
  }
}

// ======== m97-style bf16 MFMA GEMM, B^T layout; optional per-row bias ========
template<int BM, int BN, bool BF16OUT, bool ROWBIAS>
__global__ __launch_bounds__(256)
void gemm_bt(const unsigned short* __restrict__ A,
             const unsigned short* __restrict__ Bt,
             const float* __restrict__ bias,
             const int* __restrict__ ridx, const float* __restrict__ rbt,
             float* __restrict__ Cf, unsigned short* __restrict__ Cb,
             int K, int N)
{
  constexpr int BK = 32;
  __shared__ unsigned short As[BM * BK];
  __shared__ unsigned short Bs[BN * BK];
  const int tid = threadIdx.x;
  const int lane = tid & 63, wave = tid >> 6;
  const int m0 = blockIdx.x * BM, n0 = blockIdx.y * BN;
  const int wm = (wave & 1) * (BM / 2);
  const int wn = (wave >> 1) * (BN / 2);
  constexpr int FM = BM / 32, FN = BN / 32;
  constexpr int CA = (BM * 4) / 256, CB = (BN * 4) / 256;

  f32x4 acc[FM][FN] = {};
  const int fr = lane & 15;
  const int fk = (lane >> 4) * 8;

  for (int k0 = 0; k0 < K; k0 += BK) {
    __syncthreads();
    #pragma unroll
    for (int i = 0; i < CA; ++i) {
      int c = i * 256 + tid;
      const unsigned short* g = A + (size_t)(m0 + (c >> 2)) * K + k0 + (c & 3) * 8;
      __builtin_amdgcn_global_load_lds(
          (const __attribute__((address_space(1))) void*)g,
          (__attribute__((address_space(3))) void*)(As + c * 8), 16, 0, 0);
    }
    #pragma unroll
    for (int i = 0; i < CB; ++i) {
      int c = i * 256 + tid;
      const unsigned short* g = Bt + (size_t)(n0 + (c >> 2)) * K + k0 + (c & 3) * 8;
      __builtin_amdgcn_global_load_lds(
          (const __attribute__((address_space(1))) void*)g,
          (__attribute__((address_space(3))) void*)(Bs + c * 8), 16, 0, 0);
    }
    __syncthreads();
    bf16x8 af[FM], bfv[FN];
    #pragma unroll
    for (int mi = 0; mi < FM; ++mi)
      af[mi] = *(const bf16x8*)(As + (wm + mi * 16 + fr) * BK + fk);
    #pragma unroll
    for (int ni = 0; ni < FN; ++ni)
      bfv[ni] = *(const bf16x8*)(Bs + (wn + ni * 16 + fr) * BK + fk);
    #pragma unroll
    for (int mi = 0; mi < FM; ++mi)
      #pragma unroll
      for (int ni = 0; ni < FN; ++ni)
        acc[mi][ni] = __builtin_amdgcn_mfma_f32_16x16x32_bf16(
            af[mi], bfv[ni], acc[mi][ni], 0, 0, 0);
  }

  const int col16 = lane & 15, row4 = (lane >> 4) * 4;
  #pragma unroll
  for (int mi = 0; mi < FM; ++mi) {
    const int rowb = m0 + wm + mi * 16 + row4;
    int rb[4];
    if (ROWBIAS) {
      #pragma unroll
      for (int r = 0; r < 4; ++r) rb[r] = ridx[rowb + r];
    }
    #pragma unroll
    for (int ni = 0; ni < FN; ++ni) {
      int col = n0 + wn + ni * 16 + col16;
      float bv = (!ROWBIAS && bias) ? bias[col] : 0.0f;
      #pragma unroll
      for (int r = 0; r < 4; ++r) {
        float v = acc[mi][ni][r] + bv;
        if (ROWBIAS) v += rbt[(size_t)rb[r] * N + col];
        size_t off = (size_t)(rowb + r) * N + col;
        if (BF16OUT) Cb[off] = f2bf(v);
        else         Cf[off] = v;
      }
    }
  }
}

// ======== fused attention: LDS-staged QK^T MFMA + parallel softmax +
//          PV via MFMA ========
__global__ __launch_bounds__(256)
void k_attf(const unsigned short* __restrict__ cf_bf,
            const unsigned short* __restrict__ qhx,
            const float* __restrict__ mdot,
            const unsigned short* __restrict__ mem2t,
            float* __restrict__ out1, float* __restrict__ rowmax)
{
  __shared__ unsigned short As[64 * 32];
  __shared__ unsigned short Bs[80 * 32];
  __shared__ float Sbuf[64][81];
  __shared__ unsigned short w1buf[64][72];   // stride 72: 16B-aligned, spreads banks
  __shared__ float mds[64];
  const int tid = threadIdx.x, lane = tid & 63, wave = tid >> 6;
  const int m0 = blockIdx.x * 64, b = blockIdx.y;
  if (tid < 64) mds[tid] = mdot[b * NLQ + tid];
  const unsigned short* Ab = cf_bf + ((size_t)b * NNC + m0) * BD;
  const unsigned short* Bb = qhx + (size_t)b * 80 * BD;
  const int fr = lane & 15, fk = (lane >> 4) * 8;
  const int wm = wave * 16;
  f32x4 acc[5] = {};

  for (int k0 = 0; k0 < BD; k0 += 32) {
    __syncthreads();
    {
      int c = tid;   // A: 64 rows x 4 chunks = 256
      const unsigned short* g = Ab + (size_t)(c >> 2) * BD + k0 + (c & 3) * 8;
      __builtin_amdgcn_global_load_lds(
          (const __attribute__((address_space(1))) void*)g,
          (__attribute__((address_space(3))) void*)(As + c * 8), 16, 0, 0);
    }
    {
      int c = tid;   // B: 80 rows x 4 chunks = 320
      const unsigned short* g = Bb + (size_t)(c >> 2) * BD + k0 + (c & 3) * 8;
      __builtin_amdgcn_global_load_lds(
          (const __attribute__((address_space(1))) void*)g,
          (__attribute__((address_space(3))) void*)(Bs + c * 8), 16, 0, 0);
      if (tid < 64) {
        c = 256 + tid;
        g = Bb + (size_t)(c >> 2) * BD + k0 + (c & 3) * 8;
        __builtin_amdgcn_global_load_lds(
            (const __attribute__((address_space(1))) void*)g,
            (__attribute__((address_space(3))) void*)(Bs + c * 8), 16, 0, 0);
      }
    }
    __syncthreads();
    bf16x8 af = *(const bf16x8*)(As + (wm + fr) * 32 + fk);
    #pragma unroll
    for (int ni = 0; ni < 5; ++ni) {
      bf16x8 bv = *(const bf16x8*)(Bs + (ni * 16 + fr) * 32 + fk);
      acc[ni] = __builtin_amdgcn_mfma_f32_16x16x32_bf16(af, bv, acc[ni], 0, 0, 0);
    }
  }
  const int col16 = lane & 15, row4 = (lane >> 4) * 4;
  #pragma unroll
  for (int ni = 0; ni < 5; ++ni)
    #pragma unroll
    for (int r = 0; r < 4; ++r)
      Sbuf[wm + row4 + r][ni * 16 + col16] = acc[ni][r];
  __syncthreads();

  // softmax: each wave its own 16 rows; 4 lanes per row, 16 l each
  {
    const float scale = 0.03608439182435161f;    // 1/sqrt(768)
    const int r = wm + (lane >> 2);
    const int q = lane & 3;
    float e[16];
    float mx = -1e30f;
    #pragma unroll
    for (int i = 0; i < 16; ++i) {
      int l = q * 16 + i;
      float v = mds[l] + Sbuf[r][l] * scale;
      e[i] = v; mx = fmaxf(mx, v);
    }
    mx = fmaxf(mx, __shfl_xor(mx, 1));
    mx = fmaxf(mx, __shfl_xor(mx, 2));
    float s = 0.f;
    #pragma unroll
    for (int i = 0; i < 16; ++i) { e[i] = expf(e[i] - mx); s += e[i]; }
    s += __shfl_xor(s, 1);
    s += __shfl_xor(s, 2);
    float inv = 1.f / s;
    if (q == 0) rowmax[b * NNC + m0 + r] = mx + Sbuf[r][64] * scale;  // + idot
    #pragma unroll
    for (int i = 0; i < 16; ++i) w1buf[r][q * 16 + i] = f2bf(e[i] * inv);
  }
  __syncthreads();

  // PV: out1[64,192] = w1[64,64] @ mem2t[192,64]^T
  f32x4 acc2[12] = {};
  const unsigned short* Mb = mem2t + (size_t)b * HH * 64;
  #pragma unroll
  for (int kk = 0; kk < 2; ++kk) {
    bf16x8 af = *(const bf16x8*)(&w1buf[wm + fr][kk * 32 + fk]);
    #pragma unroll
    for (int ni = 0; ni < 12; ++ni) {
      bf16x8 bv = *(const bf16x8*)(Mb + (size_t)(ni * 16 + fr) * 64 + kk * 32 + fk);
      acc2[ni] = __builtin_amdgcn_mfma_f32_16x16x32_bf16(af, bv, acc2[ni], 0, 0, 0);
    }
  }
  #pragma unroll
  for (int ni = 0; ni < 12; ++ni)
    #pragma unroll
    for (int r = 0; r < 4; ++r)
      out1[(size_t)(b * NNC + m0 + wm + row4 + r) * HH + ni * 16 + col16]
          = acc2[ni][r];
}

// ======== w2 softmax over n (normalized weights) ========
__global__ __launch_bounds__(256)
void k_w2(const float* __restrict__ rowmax, float* __restrict__ w2buf)
{
  const int b = blockIdx.x, t = threadIdx.x;
  __shared__ float red[256];
  const float* rm = rowmax + (size_t)b * NNC;
  float m = -1e30f;
  for (int n = t; n < NNC; n += 256) m = fmaxf(m, rm[n]);
  red[t] = m; __syncthreads();
  for (int s = 128; s; s >>= 1) { if (t < s) red[t] = fmaxf(red[t], red[t+s]); __syncthreads(); }
  m = red[0]; __syncthreads();
  float ssum = 0.f;
  for (int n = t; n < NNC; n += 256) { float e = expf(rm[n] - m); w2buf[b*NNC + n] = e; ssum += e; }
  red[t] = ssum; __syncthreads();
  for (int s = 128; s; s >>= 1) { if (t < s) red[t] += red[t+s]; __syncthreads(); }
  float inv = 1.f / red[0];
  for (int n = t; n < NNC; n += 256) w2buf[b*NNC + n] *= inv;
}

// ======== out2 partials ========
__global__ __launch_bounds__(192)
void k_out2p(const float* __restrict__ w2buf, const float* __restrict__ inp2,
             float* __restrict__ part)
{
  const int g = blockIdx.x, b = blockIdx.y, h = threadIdx.x;
  const float* w  = w2buf + (size_t)b * NNC + g * 128;
  const float* ip = inp2 + ((size_t)b * NNC + g * 128) * HH + h;
  float acc = 0.f;
  for (int n = 0; n < 128; ++n) acc += w[n] * ip[(size_t)n * HH];
  part[((size_t)b * 16 + g) * HH + h] = acc;
}
__global__ __launch_bounds__(192)
void k_out2r(const float* __restrict__ part, float* __restrict__ out2)
{
  const int b = blockIdx.x, h = threadIdx.x;
  float acc = 0.f;
  #pragma unroll
  for (int g = 0; g < 16; ++g) acc += part[((size_t)b * 16 + g) * HH + h];
  out2[b * HH + h] = acc;
}

// ======== merged logits: blocks [0,4096) concept, [4096,6496) triple ========
__global__ __launch_bounds__(256)
void k_logits(const unsigned short* __restrict__ cf_bf, const float* __restrict__ inp2,
              const float* __restrict__ out1, const float* __restrict__ out2,
              const float* __restrict__ c_query, const float* __restrict__ t_query,
              const int* __restrict__ head_idxs, const int* __restrict__ tail_idxs,
              const int* __restrict__ rel_ids, const float* __restrict__ rtab,
              float* __restrict__ out)
{
  __shared__ float tqs[3840];
  const int blk = blockIdx.x, lane = threadIdx.x & 63, w = threadIdx.x >> 6;
  if (blk < 4096) {
    const int bn = blk * 4 + w;
    const int b = bn >> 11, n = bn & 2047;
    const float* cq  = c_query + (size_t)b * 1536;
    const unsigned short* cfr = cf_bf + (size_t)bn * BD;
    const float* i2  = inp2 + (size_t)bn * HH;
    const float* o1  = out1 + (size_t)bn * HH;
    const float* o2  = out2 + (size_t)b * HH;
    float acc = 0.f;
    for (int d = lane; d < BD; d += 64) acc += bf2f(cfr[d]) * cq[d];
    #pragma unroll
    for (int j = 0; j < 3; ++j) {
      int h = lane + 64 * j;
      float a = i2[h], o = o1[h];
      acc += a * cq[768+h] + o * cq[960+h] + a*o * cq[1152+h] + o2[h]*o * cq[1344+h];
    }
    acc = wave_sum64(acc);
    if (lane == 0) out[(size_t)b * 3248 + n] = 1.f / (1.f + expf(-acc));
  } else {
    const int blk2 = blk - 4096;
    const int b = blk2 / 300;
    const int e = (blk2 % 300) * 4 + w;
    const float* tq = t_query + (size_t)b * 3840;
    for (int i = threadIdx.x; i < 3840; i += 256) tqs[i] = tq[i];
    __syncthreads();
    const int be = b * NNE + e;
    const int hi = head_idxs[be], ti = tail_idxs[be], rid = rel_ids[be];
    const unsigned short* ch = cf_bf + ((size_t)b * NNC + hi) * BD;
    const unsigned short* ct = cf_bf + ((size_t)b * NNC + ti) * BD;
    const float* rr = rtab + (size_t)rid * BD;
    const float* i2 = inp2 + ((size_t)b * NNC + hi) * HH;
    const float* o1 = out1 + ((size_t)b * NNC + hi) * HH;
    const float* o2 = out2 + (size_t)b * HH;
    float acc = 0.f;
    for (int d = lane; d < BD; d += 64) {
      float hd = bf2f(ch[d]), td = bf2f(ct[d]);
      acc += hd * tqs[d] + rr[d] * tqs[768+d] + td * tqs[1536+d] + hd*td * tqs[2304+d];
    }
    #pragma unroll
    for (int j = 0; j < 3; ++j) {
      int h = lane + 64 * j;
      float a = i2[h], o = o1[h];
      acc += a * tqs[3072+h] + o * tqs[3264+h] + a*o * tqs[3456+h] + o2[h]*o * tqs[3648+h];
    }
    acc = wave_sum64(acc);
    if (lane == 0) out[(size_t)b * 3248 + 2048 + e] = 1.f / (1.f + expf(-acc));
  }
}

extern "C" void kernel_launch(void* const* d_in, const int* in_sizes, int n_in,
                              void* d_out, int out_size, void* d_ws, size_t ws_size,
                              hipStream_t stream) {
  const float* qh        = (const float*)d_in[0];
  const int*   head_cids = (const int*)d_in[2];
  const int*   distances = (const int*)d_in[3];
  const int*   head_idxs = (const int*)d_in[4];
  const int*   tail_idxs = (const int*)d_in[5];
  const int*   rel_ids   = (const int*)d_in[6];
  const float* ctab      = (const float*)d_in[7];
  const float* dtab      = (const float*)d_in[8];
  const float* rtab      = (const float*)d_in[9];
  const float* W_ce      = (const float*)d_in[10];
  const float* b_ce      = (const float*)d_in[11];
  const float* W_cs      = (const float*)d_in[12];
  const float* b_cs      = (const float*)d_in[13];
  const float* W_ts      = (const float*)d_in[14];
  const float* b_ts      = (const float*)d_in[15];
  const float* w_in1     = (const float*)d_in[16];
  const float* w_mem1    = (const float*)d_in[17];
  const float* W_in2     = (const float*)d_in[18];
  const float* b_in2     = (const float*)d_in[19];
  const float* W_mem2    = (const float*)d_in[20];
  const float* b_mem2    = (const float*)d_in[21];
  float* out = (float*)d_out;

  // ---- workspace layout ----
  float* fp      = (float*)d_ws;
  float* c_query = fp;                    fp += 12288;
  float* t_query = fp;                    fp += 30720;
  float* mdot    = fp;                    fp += 512;
  float* rowmax  = fp;                    fp += 16384;
  float* w2buf   = fp;                    fp += 16384;
  float* part    = fp;                    fp += 24576;
  float* out2    = fp;                    fp += 1536;
  float* qe      = fp;                    fp += 6144;     // [8][768]
  float* dcon    = fp;                    fp += 3072;     // [4][768]
  float* inp2    = fp;                    fp += 3145728;
  float* out1    = fp;                    fp += 3145728;
  unsigned short* cf_bf  = (unsigned short*)fp;
  unsigned short* Wce_t  = cf_bf  + 12582912ull;    // 768*768 (top half, transposed)
  unsigned short* Win2_t = Wce_t  + 589824ull;      // 192*768
  unsigned short* qhx    = Win2_t + 147456ull;      // 8*80*768
  unsigned short* mem2t  = qhx    + 491520ull;      // 8*192*64
  unsigned short* A_c    = mem2t  + 98304ull;       // 16384*768

  // ---- conversions / precompute ----
  k_tcvt<<<dim3(BD/32, BD/32), 256, 0, stream>>>(W_ce, Wce_t, BD, BD);
  k_tcvt<<<dim3(HH/32, BD/32), 256, 0, stream>>>(W_in2, Win2_t, BD, HH);
  k_distc<<<3, 256, 0, stream>>>(dtab, W_ce, b_ce, dcon);
  k_cvt_gather<<<(M_ROWS*96)/256, 256, 0, stream>>>(head_cids, ctab, A_c);
  k_qemb<<<dim3(NB, 2), 256, 0, stream>>>(qh, w_mem1, qe, mdot);
  k_query<<<21, 256, 0, stream>>>(qe, W_cs, b_cs, W_ts, b_ts, c_query, t_query);
  k_mem2qhx<<<(98304 + 491520)/256, 256, 0, stream>>>(qh, W_mem2, b_mem2, w_in1,
                                                      mem2t, qhx);

  // ---- MFMA GEMMs ----
  gemm_bt<128,128,true,true><<<dim3(M_ROWS/128, BD/128), 256, 0, stream>>>(
      A_c, Wce_t, nullptr, distances, dcon, nullptr, cf_bf, BD, BD);
  gemm_bt<128,64,false,false><<<dim3(M_ROWS/128, HH/64), 256, 0, stream>>>(
      cf_bf, Win2_t, b_in2, nullptr, nullptr, inp2, nullptr, BD, HH);

  // ---- fused attention ----
  k_attf<<<dim3(NNC/64, NB), 256, 0, stream>>>(cf_bf, qhx, mdot, mem2t, out1, rowmax);

  // ---- w2 / out2 / scoring ----
  k_w2<<<NB, 256, 0, stream>>>(rowmax, w2buf);
  k_out2p<<<dim3(16, NB), 192, 0, stream>>>(w2buf, inp2, part);
  k_out2r<<<NB, 192, 0, stream>>>(part, out2);
  k_logits<<<4096 + 2400, 256, 0, stream>>>(cf_bf, inp2, out1, out2, c_query, t_query,
                                            head_idxs, tail_idxs, rel_ids, rtab, out);
}

// Round 2
// 683.259 us; speedup vs baseline: 1.1501x; 1.1501x over previous
//
#include <hip/hip_runtime.h>
#include <hip/hip_bf16.h>
#include <math.h>

#define BD   768
#define HH   192
#define NB   8
#define NLQ  64
#define NNC  2048
#define NNE  1200
#define M_ROWS (NB*NNC)   // 16384

typedef float  f32x4  __attribute__((ext_vector_type(4)));
typedef short  bf16x8 __attribute__((ext_vector_type(8)));

__device__ __forceinline__ float wave_sum64(float v){
  #pragma unroll
  for (int off = 32; off; off >>= 1) v += __shfl_xor(v, off);
  return v;
}
__device__ __forceinline__ unsigned short f2bf(float f){
  union { float f; unsigned int u; } v; v.f = f;
  unsigned int u = v.u + 0x7fffu + ((v.u >> 16) & 1u);   // RNE
  return (unsigned short)(u >> 16);
}
__device__ __forceinline__ float bf2f(unsigned short h){
  union { unsigned int u; float f; } v; v.u = ((unsigned int)h) << 16; return v.f;
}
__device__ __forceinline__ unsigned int pack2(float lo, float hi){
  return ((unsigned int)f2bf(hi) << 16) | (unsigned int)f2bf(lo);
}

// ======== coalesced tiled transpose+convert: dst[C][R] = bf16(src[R][C]) ====
__global__ __launch_bounds__(256)
void k_tcvt(const float* __restrict__ src, unsigned short* __restrict__ dst,
            int R, int C){
  __shared__ float T[32][33];
  const int tx = threadIdx.x & 31, ty = threadIdx.x >> 5;   // ty 0..7
  const int c0 = blockIdx.x * 32, r0 = blockIdx.y * 32;
  #pragma unroll
  for (int i = 0; i < 4; ++i)
    T[ty + i * 8][tx] = src[(size_t)(r0 + ty + i * 8) * C + c0 + tx];
  __syncthreads();
  #pragma unroll
  for (int i = 0; i < 4; ++i)
    dst[(size_t)(c0 + ty + i * 8) * R + r0 + tx] = f2bf(T[tx][ty + i * 8]);
}

// ======== A_c[row] = bf16(ctab[cid])  (concept half only) ========
__global__ __launch_bounds__(256)
void k_cvt_gather(const int* __restrict__ cids,
                  const float* __restrict__ ctab,
                  unsigned short* __restrict__ Ac){
  int idx = blockIdx.x * 256 + threadIdx.x;        // < 16384*96
  int row = idx / 96, kc = (idx - row * 96) * 8;
  int cid = cids[row];
  const float* src = ctab + (size_t)cid * BD + kc;
  float4 f0 = ((const float4*)src)[0];
  float4 f1 = ((const float4*)src)[1];
  uint4 o;
  o.x = pack2(f0.x, f0.y); o.y = pack2(f0.z, f0.w);
  o.z = pack2(f1.x, f1.y); o.w = pack2(f1.z, f1.w);
  *(uint4*)(Ac + (size_t)row * BD + kc) = o;
}

// ======== q_emb (LDS) -> c_query/t_query ; chunk 21 = mdot ;
//          chunks 22-24 (b==0 only) = dcon[4][768] = dtab@W_ce[768:]+b_ce ====
__global__ __launch_bounds__(256)
void k_pre(const float* __restrict__ qh,
           const float* __restrict__ W_cs, const float* __restrict__ b_cs,
           const float* __restrict__ W_ts, const float* __restrict__ b_ts,
           const float* __restrict__ w_mem1,
           const float* __restrict__ W_ce, const float* __restrict__ b_ce,
           const float* __restrict__ dtab,
           float* __restrict__ c_query, float* __restrict__ t_query,
           float* __restrict__ mdot, float* __restrict__ dcon){
  const int b = blockIdx.x, chunk = blockIdx.y, t = threadIdx.x;
  if (chunk >= 22) {
    if (b != 0) return;
    const int c = (chunk - 22) * 256 + t;          // < 768
    float a0 = b_ce[c], a1 = a0, a2 = a0, a3 = a0;
    for (int d = 0; d < BD; ++d) {
      float w = W_ce[(size_t)(BD + d) * BD + c];
      a0 += dtab[d]          * w;
      a1 += dtab[BD + d]     * w;
      a2 += dtab[2 * BD + d] * w;
      a3 += dtab[3 * BD + d] * w;
    }
    dcon[c] = a0; dcon[BD + c] = a1; dcon[2 * BD + c] = a2; dcon[3 * BD + c] = a3;
    return;
  }
  if (chunk == 21) {
    if (t < NLQ) {
      const float* q = qh + ((size_t)b * NLQ + t) * BD;
      float acc = 0.f;
      #pragma unroll 4
      for (int d = 0; d < BD; d += 4) {
        float4 v = *(const float4*)(q + d);
        acc += v.x*w_mem1[d] + v.y*w_mem1[d+1] + v.z*w_mem1[d+2] + v.w*w_mem1[d+3];
      }
      mdot[b * NLQ + t] = acc;
    }
    return;
  }
  __shared__ float qe[BD];
  for (int d = t; d < BD; d += 256) {
    const float* p = qh + (size_t)b * NLQ * BD + d;
    float m = -1e30f;
    for (int l = 0; l < NLQ; ++l) m = fmaxf(m, p[(size_t)l * BD]);
    qe[d] = m;
  }
  __syncthreads();
  int j = chunk * 256 + t;
  if (j < 1536) {
    float acc = b_cs[j];
    for (int d = 0; d < BD; ++d) acc += qe[d] * W_cs[(size_t)d * 1536 + j];
    c_query[b * 1536 + j] = acc;
  } else {
    int j2 = j - 1536;
    float acc = b_ts[j2];
    for (int d = 0; d < BD; ++d) acc += qe[d] * W_ts[(size_t)d * 3840 + j2];
    t_query[b * 3840 + j2] = acc;
  }
}

// ======== mem2t[b][h][l] = bf16(qh@W_mem2 + b)  +  qhx conversion ========
__global__ __launch_bounds__(256)
void k_mem2qhx(const float* __restrict__ qh, const float* __restrict__ W_mem2,
               const float* __restrict__ b_mem2, const float* __restrict__ w_in1,
               unsigned short* __restrict__ mem2t, unsigned short* __restrict__ qhx){
  int idx = blockIdx.x * 256 + threadIdx.x;        // < 98304 + 491520
  if (idx < 98304) {
    int h = idx % HH, bl = idx / HH;               // bl = b*64 + l
    int b = bl >> 6, l = bl & 63;
    const float* q = qh + (size_t)bl * BD;
    float acc = b_mem2[h];
    for (int d = 0; d < BD; ++d) acc += q[d] * W_mem2[(size_t)d * HH + h];
    mem2t[((size_t)b * HH + h) * 64 + l] = f2bf(acc);
  } else {
    int i = idx - 98304;
    int b = i / 61440, rk = i - b * 61440;
    int r = rk / BD, k = rk - r * BD;
    unsigned short v;
    if (r < 64)       v = f2bf(qh[((size_t)b * NLQ + r) * BD + k]);
    else if (r == 64) v = f2bf(w_in1[k] * 27.712812921102035f);  // sqrt(768)
    else              v = 0;
    qhx[i] = v;
  }
}

// ======== m97-style bf16 MFMA GEMM, B^T layout; optional per-row bias ========
template<int BM, int BN, bool BF16OUT, bool ROWBIAS>
__global__ __launch_bounds__(256)
void gemm_bt(const unsigned short* __restrict__ A,
             const unsigned short* __restrict__ Bt,
             const float* __restrict__ bias,
             const int* __restrict__ ridx, const float* __restrict__ rbt,
             float* __restrict__ Cf, unsigned short* __restrict__ Cb,
             int K, int N)
{
  constexpr int BK = 32;
  __shared__ unsigned short As[BM * BK];
  __shared__ unsigned short Bs[BN * BK];
  const int tid = threadIdx.x;
  const int lane = tid & 63, wave = tid >> 6;
  const int m0 = blockIdx.x * BM, n0 = blockIdx.y * BN;
  const int wm = (wave & 1) * (BM / 2);
  const int wn = (wave >> 1) * (BN / 2);
  constexpr int FM = BM / 32, FN = BN / 32;
  constexpr int CA = (BM * 4) / 256, CB = (BN * 4) / 256;

  f32x4 acc[FM][FN] = {};
  const int fr = lane & 15;
  const int fk = (lane >> 4) * 8;

  for (int k0 = 0; k0 < K; k0 += BK) {
    __syncthreads();
    #pragma unroll
    for (int i = 0; i < CA; ++i) {
      int c = i * 256 + tid;
      const unsigned short* g = A + (size_t)(m0 + (c >> 2)) * K + k0 + (c & 3) * 8;
      __builtin_amdgcn_global_load_lds(
          (const __attribute__((address_space(1))) void*)g,
          (__attribute__((address_space(3))) void*)(As + c * 8), 16, 0, 0);
    }
    #pragma unroll
    for (int i = 0; i < CB; ++i) {
      int c = i * 256 + tid;
      const unsigned short* g = Bt + (size_t)(n0 + (c >> 2)) * K + k0 + (c & 3) * 8;
      __builtin_amdgcn_global_load_lds(
          (const __attribute__((address_space(1))) void*)g,
          (__attribute__((address_space(3))) void*)(Bs + c * 8), 16, 0, 0);
    }
    __syncthreads();
    bf16x8 af[FM], bfv[FN];
    #pragma unroll
    for (int mi = 0; mi < FM; ++mi)
      af[mi] = *(const bf16x8*)(As + (wm + mi * 16 + fr) * BK + fk);
    #pragma unroll
    for (int ni = 0; ni < FN; ++ni)
      bfv[ni] = *(const bf16x8*)(Bs + (wn + ni * 16 + fr) * BK + fk);
    #pragma unroll
    for (int mi = 0; mi < FM; ++mi)
      #pragma unroll
      for (int ni = 0; ni < FN; ++ni)
        acc[mi][ni] = __builtin_amdgcn_mfma_f32_16x16x32_bf16(
            af[mi], bfv[ni], acc[mi][ni], 0, 0, 0);
  }

  const int col16 = lane & 15, row4 = (lane >> 4) * 4;
  #pragma unroll
  for (int mi = 0; mi < FM; ++mi) {
    const int rowb = m0 + wm + mi * 16 + row4;
    int rb[4];
    if (ROWBIAS) {
      #pragma unroll
      for (int r = 0; r < 4; ++r) rb[r] = ridx[rowb + r];
    }
    #pragma unroll
    for (int ni = 0; ni < FN; ++ni) {
      int col = n0 + wn + ni * 16 + col16;
      float bv = (!ROWBIAS && bias) ? bias[col] : 0.0f;
      #pragma unroll
      for (int r = 0; r < 4; ++r) {
        float v = acc[mi][ni][r] + bv;
        if (ROWBIAS) v += rbt[(size_t)rb[r] * N + col];
        size_t off = (size_t)(rowb + r) * N + col;
        if (BF16OUT) Cb[off] = f2bf(v);
        else         Cf[off] = v;
      }
    }
  }
}

// ======== fused attention: LDS-staged QK^T MFMA + parallel softmax +
//          PV via MFMA ========
__global__ __launch_bounds__(256)
void k_attf(const unsigned short* __restrict__ cf_bf,
            const unsigned short* __restrict__ qhx,
            const float* __restrict__ mdot,
            const unsigned short* __restrict__ mem2t,
            float* __restrict__ out1, float* __restrict__ rowmax)
{
  __shared__ unsigned short As[64 * 32];
  __shared__ unsigned short Bs[80 * 32];
  __shared__ float Sbuf[64][81];
  __shared__ unsigned short w1buf[64][72];   // stride 72: 16B-aligned, spreads banks
  __shared__ float mds[64];
  const int tid = threadIdx.x, lane = tid & 63, wave = tid >> 6;
  const int m0 = blockIdx.x * 64, b = blockIdx.y;
  if (tid < 64) mds[tid] = mdot[b * NLQ + tid];
  const unsigned short* Ab = cf_bf + ((size_t)b * NNC + m0) * BD;
  const unsigned short* Bb = qhx + (size_t)b * 80 * BD;
  const int fr = lane & 15, fk = (lane >> 4) * 8;
  const int wm = wave * 16;
  f32x4 acc[5] = {};

  for (int k0 = 0; k0 < BD; k0 += 32) {
    __syncthreads();
    {
      int c = tid;   // A: 64 rows x 4 chunks = 256
      const unsigned short* g = Ab + (size_t)(c >> 2) * BD + k0 + (c & 3) * 8;
      __builtin_amdgcn_global_load_lds(
          (const __attribute__((address_space(1))) void*)g,
          (__attribute__((address_space(3))) void*)(As + c * 8), 16, 0, 0);
    }
    {
      int c = tid;   // B: 80 rows x 4 chunks = 320
      const unsigned short* g = Bb + (size_t)(c >> 2) * BD + k0 + (c & 3) * 8;
      __builtin_amdgcn_global_load_lds(
          (const __attribute__((address_space(1))) void*)g,
          (__attribute__((address_space(3))) void*)(Bs + c * 8), 16, 0, 0);
      if (tid < 64) {
        c = 256 + tid;
        g = Bb + (size_t)(c >> 2) * BD + k0 + (c & 3) * 8;
        __builtin_amdgcn_global_load_lds(
            (const __attribute__((address_space(1))) void*)g,
            (__attribute__((address_space(3))) void*)(Bs + c * 8), 16, 0, 0);
      }
    }
    __syncthreads();
    bf16x8 af = *(const bf16x8*)(As + (wm + fr) * 32 + fk);
    #pragma unroll
    for (int ni = 0; ni < 5; ++ni) {
      bf16x8 bv = *(const bf16x8*)(Bs + (ni * 16 + fr) * 32 + fk);
      acc[ni] = __builtin_amdgcn_mfma_f32_16x16x32_bf16(af, bv, acc[ni], 0, 0, 0);
    }
  }
  const int col16 = lane & 15, row4 = (lane >> 4) * 4;
  #pragma unroll
  for (int ni = 0; ni < 5; ++ni)
    #pragma unroll
    for (int r = 0; r < 4; ++r)
      Sbuf[wm + row4 + r][ni * 16 + col16] = acc[ni][r];
  __syncthreads();

  // softmax: each wave its own 16 rows; 4 lanes per row, 16 l each
  {
    const float scale = 0.03608439182435161f;    // 1/sqrt(768)
    const int r = wm + (lane >> 2);
    const int q = lane & 3;
    float e[16];
    float mx = -1e30f;
    #pragma unroll
    for (int i = 0; i < 16; ++i) {
      int l = q * 16 + i;
      float v = mds[l] + Sbuf[r][l] * scale;
      e[i] = v; mx = fmaxf(mx, v);
    }
    mx = fmaxf(mx, __shfl_xor(mx, 1));
    mx = fmaxf(mx, __shfl_xor(mx, 2));
    float s = 0.f;
    #pragma unroll
    for (int i = 0; i < 16; ++i) { e[i] = expf(e[i] - mx); s += e[i]; }
    s += __shfl_xor(s, 1);
    s += __shfl_xor(s, 2);
    float inv = 1.f / s;
    if (q == 0) rowmax[b * NNC + m0 + r] = mx + Sbuf[r][64] * scale;  // + idot
    #pragma unroll
    for (int i = 0; i < 16; ++i) w1buf[r][q * 16 + i] = f2bf(e[i] * inv);
  }
  __syncthreads();

  // PV: out1[64,192] = w1[64,64] @ mem2t[192,64]^T
  f32x4 acc2[12] = {};
  const unsigned short* Mb = mem2t + (size_t)b * HH * 64;
  #pragma unroll
  for (int kk = 0; kk < 2; ++kk) {
    bf16x8 af = *(const bf16x8*)(&w1buf[wm + fr][kk * 32 + fk]);
    #pragma unroll
    for (int ni = 0; ni < 12; ++ni) {
      bf16x8 bv = *(const bf16x8*)(Mb + (size_t)(ni * 16 + fr) * 64 + kk * 32 + fk);
      acc2[ni] = __builtin_amdgcn_mfma_f32_16x16x32_bf16(af, bv, acc2[ni], 0, 0, 0);
    }
  }
  #pragma unroll
  for (int ni = 0; ni < 12; ++ni)
    #pragma unroll
    for (int r = 0; r < 4; ++r)
      out1[(size_t)(b * NNC + m0 + wm + row4 + r) * HH + ni * 16 + col16]
          = acc2[ni][r];
}

// ======== w2 softmax over n (normalized weights) ========
__global__ __launch_bounds__(256)
void k_w2(const float* __restrict__ rowmax, float* __restrict__ w2buf)
{
  const int b = blockIdx.x, t = threadIdx.x;
  __shared__ float red[256];
  const float* rm = rowmax + (size_t)b * NNC;
  float m = -1e30f;
  for (int n = t; n < NNC; n += 256) m = fmaxf(m, rm[n]);
  red[t] = m; __syncthreads();
  for (int s = 128; s; s >>= 1) { if (t < s) red[t] = fmaxf(red[t], red[t+s]); __syncthreads(); }
  m = red[0]; __syncthreads();
  float ssum = 0.f;
  for (int n = t; n < NNC; n += 256) { float e = expf(rm[n] - m); w2buf[b*NNC + n] = e; ssum += e; }
  red[t] = ssum; __syncthreads();
  for (int s = 128; s; s >>= 1) { if (t < s) red[t] += red[t+s]; __syncthreads(); }
  float inv = 1.f / red[0];
  for (int n = t; n < NNC; n += 256) w2buf[b*NNC + n] *= inv;
}

// ======== out2 partials ========
__global__ __launch_bounds__(192)
void k_out2p(const float* __restrict__ w2buf, const float* __restrict__ inp2,
             float* __restrict__ part)
{
  const int g = blockIdx.x, b = blockIdx.y, h = threadIdx.x;
  const float* w  = w2buf + (size_t)b * NNC + g * 128;
  const float* ip = inp2 + ((size_t)b * NNC + g * 128) * HH + h;
  float acc = 0.f;
  for (int n = 0; n < 128; ++n) acc += w[n] * ip[(size_t)n * HH];
  part[((size_t)b * 16 + g) * HH + h] = acc;
}
__global__ __launch_bounds__(192)
void k_out2r(const float* __restrict__ part, float* __restrict__ out2)
{
  const int b = blockIdx.x, h = threadIdx.x;
  float acc = 0.f;
  #pragma unroll
  for (int g = 0; g < 16; ++g) acc += part[((size_t)b * 16 + g) * HH + h];
  out2[b * HH + h] = acc;
}

// ======== merged logits: blocks [0,4096) concept, [4096,6496) triple ========
__global__ __launch_bounds__(256)
void k_logits(const unsigned short* __restrict__ cf_bf, const float* __restrict__ inp2,
              const float* __restrict__ out1, const float* __restrict__ out2,
              const float* __restrict__ c_query, const float* __restrict__ t_query,
              const int* __restrict__ head_idxs, const int* __restrict__ tail_idxs,
              const int* __restrict__ rel_ids, const float* __restrict__ rtab,
              float* __restrict__ out)
{
  __shared__ float tqs[3840];
  const int blk = blockIdx.x, lane = threadIdx.x & 63, w = threadIdx.x >> 6;
  if (blk < 4096) {
    const int bn = blk * 4 + w;
    const int b = bn >> 11, n = bn & 2047;
    const float* cq  = c_query + (size_t)b * 1536;
    const unsigned short* cfr = cf_bf + (size_t)bn * BD;
    const float* i2  = inp2 + (size_t)bn * HH;
    const float* o1  = out1 + (size_t)bn * HH;
    const float* o2  = out2 + (size_t)b * HH;
    float acc = 0.f;
    for (int d = lane; d < BD; d += 64) acc += bf2f(cfr[d]) * cq[d];
    #pragma unroll
    for (int j = 0; j < 3; ++j) {
      int h = lane + 64 * j;
      float a = i2[h], o = o1[h];
      acc += a * cq[768+h] + o * cq[960+h] + a*o * cq[1152+h] + o2[h]*o * cq[1344+h];
    }
    acc = wave_sum64(acc);
    if (lane == 0) out[(size_t)b * 3248 + n] = 1.f / (1.f + expf(-acc));
  } else {
    const int blk2 = blk - 4096;
    const int b = blk2 / 300;
    const int e = (blk2 % 300) * 4 + w;
    const float* tq = t_query + (size_t)b * 3840;
    for (int i = threadIdx.x; i < 3840; i += 256) tqs[i] = tq[i];
    __syncthreads();
    const int be = b * NNE + e;
    const int hi = head_idxs[be], ti = tail_idxs[be], rid = rel_ids[be];
    const unsigned short* ch = cf_bf + ((size_t)b * NNC + hi) * BD;
    const unsigned short* ct = cf_bf + ((size_t)b * NNC + ti) * BD;
    const float* rr = rtab + (size_t)rid * BD;
    const float* i2 = inp2 + ((size_t)b * NNC + hi) * HH;
    const float* o1 = out1 + ((size_t)b * NNC + hi) * HH;
    const float* o2 = out2 + (size_t)b * HH;
    float acc = 0.f;
    for (int d = lane; d < BD; d += 64) {
      float hd = bf2f(ch[d]), td = bf2f(ct[d]);
      acc += hd * tqs[d] + rr[d] * tqs[768+d] + td * tqs[1536+d] + hd*td * tqs[2304+d];
    }
    #pragma unroll
    for (int j = 0; j < 3; ++j) {
      int h = lane + 64 * j;
      float a = i2[h], o = o1[h];
      acc += a * tqs[3072+h] + o * tqs[3264+h] + a*o * tqs[3456+h] + o2[h]*o * tqs[3648+h];
    }
    acc = wave_sum64(acc);
    if (lane == 0) out[(size_t)b * 3248 + 2048 + e] = 1.f / (1.f + expf(-acc));
  }
}

extern "C" void kernel_launch(void* const* d_in, const int* in_sizes, int n_in,
                              void* d_out, int out_size, void* d_ws, size_t ws_size,
                              hipStream_t stream) {
  const float* qh        = (const float*)d_in[0];
  const int*   head_cids = (const int*)d_in[2];
  const int*   distances = (const int*)d_in[3];
  const int*   head_idxs = (const int*)d_in[4];
  const int*   tail_idxs = (const int*)d_in[5];
  const int*   rel_ids   = (const int*)d_in[6];
  const float* ctab      = (const float*)d_in[7];
  const float* dtab      = (const float*)d_in[8];
  const float* rtab      = (const float*)d_in[9];
  const float* W_ce      = (const float*)d_in[10];
  const float* b_ce      = (const float*)d_in[11];
  const float* W_cs      = (const float*)d_in[12];
  const float* b_cs      = (const float*)d_in[13];
  const float* W_ts      = (const float*)d_in[14];
  const float* b_ts      = (const float*)d_in[15];
  const float* w_in1     = (const float*)d_in[16];
  const float* w_mem1    = (const float*)d_in[17];
  const float* W_in2     = (const float*)d_in[18];
  const float* b_in2     = (const float*)d_in[19];
  const float* W_mem2    = (const float*)d_in[20];
  const float* b_mem2    = (const float*)d_in[21];
  float* out = (float*)d_out;

  // ---- workspace layout ----
  float* fp      = (float*)d_ws;
  float* c_query = fp;                    fp += 12288;
  float* t_query = fp;                    fp += 30720;
  float* mdot    = fp;                    fp += 512;
  float* rowmax  = fp;                    fp += 16384;
  float* w2buf   = fp;                    fp += 16384;
  float* part    = fp;                    fp += 24576;
  float* out2    = fp;                    fp += 1536;
  float* dcon    = fp;                    fp += 3072;     // [4][768]
  float* inp2    = fp;                    fp += 3145728;
  float* out1    = fp;                    fp += 3145728;
  unsigned short* cf_bf  = (unsigned short*)fp;
  unsigned short* Wce_t  = cf_bf  + 12582912ull;    // 768*768 (top half, transposed)
  unsigned short* Win2_t = Wce_t  + 589824ull;      // 192*768
  unsigned short* qhx    = Win2_t + 147456ull;      // 8*80*768
  unsigned short* mem2t  = qhx    + 491520ull;      // 8*192*64
  unsigned short* A_c    = mem2t  + 98304ull;       // 16384*768

  // ---- conversions / precompute ----
  k_tcvt<<<dim3(BD/32, BD/32), 256, 0, stream>>>(W_ce, Wce_t, BD, BD);
  k_tcvt<<<dim3(HH/32, BD/32), 256, 0, stream>>>(W_in2, Win2_t, BD, HH);
  k_cvt_gather<<<(M_ROWS*96)/256, 256, 0, stream>>>(head_cids, ctab, A_c);
  k_pre<<<dim3(NB, 25), 256, 0, stream>>>(qh, W_cs, b_cs, W_ts, b_ts, w_mem1,
                                          W_ce, b_ce, dtab,
                                          c_query, t_query, mdot, dcon);
  k_mem2qhx<<<(98304 + 491520)/256, 256, 0, stream>>>(qh, W_mem2, b_mem2, w_in1,
                                                      mem2t, qhx);

  // ---- MFMA GEMMs ----
  gemm_bt<128,128,true,true><<<dim3(M_ROWS/128, BD/128), 256, 0, stream>>>(
      A_c, Wce_t, nullptr, distances, dcon, nullptr, cf_bf, BD, BD);
  gemm_bt<128,64,false,false><<<dim3(M_ROWS/128, HH/64), 256, 0, stream>>>(
      cf_bf, Win2_t, b_in2, nullptr, nullptr, inp2, nullptr, BD, HH);

  // ---- fused attention ----
  k_attf<<<dim3(NNC/64, NB), 256, 0, stream>>>(cf_bf, qhx, mdot, mem2t, out1, rowmax);

  // ---- w2 / out2 / scoring ----
  k_w2<<<NB, 256, 0, stream>>>(rowmax, w2buf);
  k_out2p<<<dim3(16, NB), 192, 0, stream>>>(w2buf, inp2, part);
  k_out2r<<<NB, 192, 0, stream>>>(part, out2);
  k_logits<<<4096 + 2400, 256, 0, stream>>>(cf_bf, inp2, out1, out2, c_query, t_query,
                                            head_idxs, tail_idxs, rel_ids, rtab, out);
}

// Round 3
// 669.774 us; speedup vs baseline: 1.1733x; 1.0201x over previous
//
#include <hip/hip_runtime.h>
#include <hip/hip_bf16.h>
#include <math.h>

#define BD   768
#define HH   192
#define NB   8
#define NLQ  64
#define NNC  2048
#define NNE  1200
#define M_ROWS (NB*NNC)   // 16384
#define KAUG 800          // 768 + 32 (one-hot dist slots, zero-padded)

typedef float  f32x4  __attribute__((ext_vector_type(4)));
typedef short  bf16x8 __attribute__((ext_vector_type(8)));

__device__ __forceinline__ float wave_sum64(float v){
  #pragma unroll
  for (int off = 32; off; off >>= 1) v += __shfl_xor(v, off);
  return v;
}
__device__ __forceinline__ unsigned short f2bf(float f){
  union { float f; unsigned int u; } v; v.f = f;
  unsigned int u = v.u + 0x7fffu + ((v.u >> 16) & 1u);   // RNE
  return (unsigned short)(u >> 16);
}
__device__ __forceinline__ float bf2f(unsigned short h){
  union { unsigned int u; float f; } v; v.u = ((unsigned int)h) << 16; return v.f;
}
__device__ __forceinline__ unsigned int pack2(float lo, float hi){
  return ((unsigned int)f2bf(hi) << 16) | (unsigned int)f2bf(lo);
}

// ==== coalesced tiled transpose+convert: dst[C][R..] = bf16(src[R][C]),
//      dst row stride SD (elements) ====
__global__ __launch_bounds__(256)
void k_tcvt(const float* __restrict__ src, unsigned short* __restrict__ dst,
            int R, int C, int SD){
  __shared__ float T[32][33];
  const int tx = threadIdx.x & 31, ty = threadIdx.x >> 5;   // ty 0..7
  const int c0 = blockIdx.x * 32, r0 = blockIdx.y * 32;
  #pragma unroll
  for (int i = 0; i < 4; ++i)
    T[ty + i * 8][tx] = src[(size_t)(r0 + ty + i * 8) * C + c0 + tx];
  __syncthreads();
  #pragma unroll
  for (int i = 0; i < 4; ++i)
    dst[(size_t)(c0 + ty + i * 8) * SD + r0 + tx] = f2bf(T[tx][ty + i * 8]);
}

// ======== q_emb (LDS) -> c_query/t_query ; chunk 21 = mdot ;
//          chunks 22-24 (b==0 only) = dcon[4][768] = dtab@W_ce[768:]+b_ce ====
__global__ __launch_bounds__(256)
void k_pre(const float* __restrict__ qh,
           const float* __restrict__ W_cs, const float* __restrict__ b_cs,
           const float* __restrict__ W_ts, const float* __restrict__ b_ts,
           const float* __restrict__ w_mem1,
           const float* __restrict__ W_ce, const float* __restrict__ b_ce,
           const float* __restrict__ dtab,
           float* __restrict__ c_query, float* __restrict__ t_query,
           float* __restrict__ mdot, float* __restrict__ dcon){
  const int b = blockIdx.x, chunk = blockIdx.y, t = threadIdx.x;
  if (chunk >= 22) {
    if (b != 0) return;
    const int c = (chunk - 22) * 256 + t;          // < 768
    float a0 = b_ce[c], a1 = a0, a2 = a0, a3 = a0;
    for (int d = 0; d < BD; ++d) {
      float w = W_ce[(size_t)(BD + d) * BD + c];
      a0 += dtab[d]          * w;
      a1 += dtab[BD + d]     * w;
      a2 += dtab[2 * BD + d] * w;
      a3 += dtab[3 * BD + d] * w;
    }
    dcon[c] = a0; dcon[BD + c] = a1; dcon[2 * BD + c] = a2; dcon[3 * BD + c] = a3;
    return;
  }
  if (chunk == 21) {
    if (t < NLQ) {
      const float* q = qh + ((size_t)b * NLQ + t) * BD;
      float acc = 0.f;
      #pragma unroll 4
      for (int d = 0; d < BD; d += 4) {
        float4 v = *(const float4*)(q + d);
        acc += v.x*w_mem1[d] + v.y*w_mem1[d+1] + v.z*w_mem1[d+2] + v.w*w_mem1[d+3];
      }
      mdot[b * NLQ + t] = acc;
    }
    return;
  }
  __shared__ float qe[BD];
  for (int d = t; d < BD; d += 256) {
    const float* p = qh + (size_t)b * NLQ * BD + d;
    float m = -1e30f;
    for (int l = 0; l < NLQ; ++l) m = fmaxf(m, p[(size_t)l * BD]);
    qe[d] = m;
  }
  __syncthreads();
  int j = chunk * 256 + t;
  if (j < 1536) {
    float acc = b_cs[j];
    for (int d = 0; d < BD; ++d) acc += qe[d] * W_cs[(size_t)d * 1536 + j];
    c_query[b * 1536 + j] = acc;
  } else {
    int j2 = j - 1536;
    float acc = b_ts[j2];
    for (int d = 0; d < BD; ++d) acc += qe[d] * W_ts[(size_t)d * 3840 + j2];
    t_query[b * 3840 + j2] = acc;
  }
}

// ======== A_aug[row] = bf16(ctab[cid]) ++ onehot(dist) ++ zeros ;
//          tail range fills Bt_aug cols [768,800) from dcon ========
__global__ __launch_bounds__(256)
void k_cvt_gather(const int* __restrict__ cids, const int* __restrict__ dsts,
                  const float* __restrict__ ctab, const float* __restrict__ dcon,
                  unsigned short* __restrict__ Aaug, unsigned short* __restrict__ Btaug){
  int idx = blockIdx.x * 256 + threadIdx.x;        // < 16384*100 + 24576
  if (idx < M_ROWS * 100) {
    int row = idx / 100, kc = idx - row * 100;     // kc: chunk of 8 elems
    unsigned short* dst = Aaug + (size_t)row * KAUG + kc * 8;
    if (kc < 96) {
      int cid = cids[row];
      const float* src = ctab + (size_t)cid * BD + kc * 8;
      float4 f0 = ((const float4*)src)[0];
      float4 f1 = ((const float4*)src)[1];
      uint4 o;
      o.x = pack2(f0.x, f0.y); o.y = pack2(f0.z, f0.w);
      o.z = pack2(f1.x, f1.y); o.w = pack2(f1.z, f1.w);
      *(uint4*)dst = o;
    } else if (kc == 96) {
      int d = dsts[row];                           // 0..3
      uint4 o;
      o.x = (d == 0 ? 0x3F80u : 0u) | (d == 1 ? 0x3F800000u : 0u);
      o.y = (d == 2 ? 0x3F80u : 0u) | (d == 3 ? 0x3F800000u : 0u);
      o.z = 0u; o.w = 0u;
      *(uint4*)dst = o;
    } else {
      uint4 z = {0u, 0u, 0u, 0u};
      *(uint4*)dst = z;
    }
  } else {
    int e = idx - M_ROWS * 100;                    // < 768*32
    int col = e >> 5, k = e & 31;
    Btaug[(size_t)col * KAUG + BD + k] =
        (k < 4) ? f2bf(dcon[(size_t)k * BD + col]) : (unsigned short)0;
  }
}

// ======== mem2t[b][h][l] = bf16(qh@W_mem2 + b)  +  qhx conversion ========
__global__ __launch_bounds__(256)
void k_mem2qhx(const float* __restrict__ qh, const float* __restrict__ W_mem2,
               const float* __restrict__ b_mem2, const float* __restrict__ w_in1,
               unsigned short* __restrict__ mem2t, unsigned short* __restrict__ qhx){
  int idx = blockIdx.x * 256 + threadIdx.x;        // < 98304 + 491520
  if (idx < 98304) {
    int h = idx % HH, bl = idx / HH;               // bl = b*64 + l
    int b = bl >> 6, l = bl & 63;
    const float* q = qh + (size_t)bl * BD;
    float acc = b_mem2[h];
    for (int d = 0; d < BD; ++d) acc += q[d] * W_mem2[(size_t)d * HH + h];
    mem2t[((size_t)b * HH + h) * 64 + l] = f2bf(acc);
  } else {
    int i = idx - 98304;
    int b = i / 61440, rk = i - b * 61440;
    int r = rk / BD, k = rk - r * BD;
    unsigned short v;
    if (r < 64)       v = f2bf(qh[((size_t)b * NLQ + r) * BD + k]);
    else if (r == 64) v = f2bf(w_in1[k] * 27.712812921102035f);  // sqrt(768)
    else              v = 0;
    qhx[i] = v;
  }
}

// ======== m97-style bf16 MFMA GEMM, B^T layout (round-0 epilogue) ========
template<int BM, int BN, bool BF16OUT>
__global__ __launch_bounds__(256)
void gemm_bt(const unsigned short* __restrict__ A,
             const unsigned short* __restrict__ Bt,
             const float* __restrict__ bias,
             float* __restrict__ Cf, unsigned short* __restrict__ Cb,
             int K, int N)
{
  constexpr int BK = 32;
  __shared__ unsigned short As[BM * BK];
  __shared__ unsigned short Bs[BN * BK];
  const int tid = threadIdx.x;
  const int lane = tid & 63, wave = tid >> 6;
  const int m0 = blockIdx.x * BM, n0 = blockIdx.y * BN;
  const int wm = (wave & 1) * (BM / 2);
  const int wn = (wave >> 1) * (BN / 2);
  constexpr int FM = BM / 32, FN = BN / 32;
  constexpr int CA = (BM * 4) / 256, CB = (BN * 4) / 256;

  f32x4 acc[FM][FN] = {};
  const int fr = lane & 15;
  const int fk = (lane >> 4) * 8;

  for (int k0 = 0; k0 < K; k0 += BK) {
    __syncthreads();
    #pragma unroll
    for (int i = 0; i < CA; ++i) {
      int c = i * 256 + tid;
      const unsigned short* g = A + (size_t)(m0 + (c >> 2)) * K + k0 + (c & 3) * 8;
      __builtin_amdgcn_global_load_lds(
          (const __attribute__((address_space(1))) void*)g,
          (__attribute__((address_space(3))) void*)(As + c * 8), 16, 0, 0);
    }
    #pragma unroll
    for (int i = 0; i < CB; ++i) {
      int c = i * 256 + tid;
      const unsigned short* g = Bt + (size_t)(n0 + (c >> 2)) * K + k0 + (c & 3) * 8;
      __builtin_amdgcn_global_load_lds(
          (const __attribute__((address_space(1))) void*)g,
          (__attribute__((address_space(3))) void*)(Bs + c * 8), 16, 0, 0);
    }
    __syncthreads();
    bf16x8 af[FM], bfv[FN];
    #pragma unroll
    for (int mi = 0; mi < FM; ++mi)
      af[mi] = *(const bf16x8*)(As + (wm + mi * 16 + fr) * BK + fk);
    #pragma unroll
    for (int ni = 0; ni < FN; ++ni)
      bfv[ni] = *(const bf16x8*)(Bs + (wn + ni * 16 + fr) * BK + fk);
    #pragma unroll
    for (int mi = 0; mi < FM; ++mi)
      #pragma unroll
      for (int ni = 0; ni < FN; ++ni)
        acc[mi][ni] = __builtin_amdgcn_mfma_f32_16x16x32_bf16(
            af[mi], bfv[ni], acc[mi][ni], 0, 0, 0);
  }

  const int col16 = lane & 15, row4 = (lane >> 4) * 4;
  #pragma unroll
  for (int mi = 0; mi < FM; ++mi) {
    #pragma unroll
    for (int ni = 0; ni < FN; ++ni) {
      int col = n0 + wn + ni * 16 + col16;
      float bv = bias ? bias[col] : 0.0f;
      int rowb = m0 + wm + mi * 16 + row4;
      #pragma unroll
      for (int r = 0; r < 4; ++r) {
        float v = acc[mi][ni][r] + bv;
        size_t off = (size_t)(rowb + r) * N + col;
        if (BF16OUT) Cb[off] = f2bf(v);
        else         Cf[off] = v;
      }
    }
  }
}

// ======== fused attention: LDS-staged QK^T MFMA + parallel softmax +
//          PV via MFMA ========
__global__ __launch_bounds__(256)
void k_attf(const unsigned short* __restrict__ cf_bf,
            const unsigned short* __restrict__ qhx,
            const float* __restrict__ mdot,
            const unsigned short* __restrict__ mem2t,
            float* __restrict__ out1, float* __restrict__ rowmax)
{
  __shared__ unsigned short As[64 * 32];
  __shared__ unsigned short Bs[80 * 32];
  __shared__ float Sbuf[64][81];
  __shared__ unsigned short w1buf[64][72];   // stride 72: 16B-aligned, spreads banks
  __shared__ float mds[64];
  const int tid = threadIdx.x, lane = tid & 63, wave = tid >> 6;
  const int m0 = blockIdx.x * 64, b = blockIdx.y;
  if (tid < 64) mds[tid] = mdot[b * NLQ + tid];
  const unsigned short* Ab = cf_bf + ((size_t)b * NNC + m0) * BD;
  const unsigned short* Bb = qhx + (size_t)b * 80 * BD;
  const int fr = lane & 15, fk = (lane >> 4) * 8;
  const int wm = wave * 16;
  f32x4 acc[5] = {};

  for (int k0 = 0; k0 < BD; k0 += 32) {
    __syncthreads();
    {
      int c = tid;   // A: 64 rows x 4 chunks = 256
      const unsigned short* g = Ab + (size_t)(c >> 2) * BD + k0 + (c & 3) * 8;
      __builtin_amdgcn_global_load_lds(
          (const __attribute__((address_space(1))) void*)g,
          (__attribute__((address_space(3))) void*)(As + c * 8), 16, 0, 0);
    }
    {
      int c = tid;   // B: 80 rows x 4 chunks = 320
      const unsigned short* g = Bb + (size_t)(c >> 2) * BD + k0 + (c & 3) * 8;
      __builtin_amdgcn_global_load_lds(
          (const __attribute__((address_space(1))) void*)g,
          (__attribute__((address_space(3))) void*)(Bs + c * 8), 16, 0, 0);
      if (tid < 64) {
        c = 256 + tid;
        g = Bb + (size_t)(c >> 2) * BD + k0 + (c & 3) * 8;
        __builtin_amdgcn_global_load_lds(
            (const __attribute__((address_space(1))) void*)g,
            (__attribute__((address_space(3))) void*)(Bs + c * 8), 16, 0, 0);
      }
    }
    __syncthreads();
    bf16x8 af = *(const bf16x8*)(As + (wm + fr) * 32 + fk);
    #pragma unroll
    for (int ni = 0; ni < 5; ++ni) {
      bf16x8 bv = *(const bf16x8*)(Bs + (ni * 16 + fr) * 32 + fk);
      acc[ni] = __builtin_amdgcn_mfma_f32_16x16x32_bf16(af, bv, acc[ni], 0, 0, 0);
    }
  }
  const int col16 = lane & 15, row4 = (lane >> 4) * 4;
  #pragma unroll
  for (int ni = 0; ni < 5; ++ni)
    #pragma unroll
    for (int r = 0; r < 4; ++r)
      Sbuf[wm + row4 + r][ni * 16 + col16] = acc[ni][r];
  __syncthreads();

  // softmax: each wave its own 16 rows; 4 lanes per row, 16 l each
  {
    const float scale = 0.03608439182435161f;    // 1/sqrt(768)
    const int r = wm + (lane >> 2);
    const int q = lane & 3;
    float e[16];
    float mx = -1e30f;
    #pragma unroll
    for (int i = 0; i < 16; ++i) {
      int l = q * 16 + i;
      float v = mds[l] + Sbuf[r][l] * scale;
      e[i] = v; mx = fmaxf(mx, v);
    }
    mx = fmaxf(mx, __shfl_xor(mx, 1));
    mx = fmaxf(mx, __shfl_xor(mx, 2));
    float s = 0.f;
    #pragma unroll
    for (int i = 0; i < 16; ++i) { e[i] = expf(e[i] - mx); s += e[i]; }
    s += __shfl_xor(s, 1);
    s += __shfl_xor(s, 2);
    float inv = 1.f / s;
    if (q == 0) rowmax[b * NNC + m0 + r] = mx + Sbuf[r][64] * scale;  // + idot
    #pragma unroll
    for (int i = 0; i < 16; ++i) w1buf[r][q * 16 + i] = f2bf(e[i] * inv);
  }
  __syncthreads();

  // PV: out1[64,192] = w1[64,64] @ mem2t[192,64]^T
  f32x4 acc2[12] = {};
  const unsigned short* Mb = mem2t + (size_t)b * HH * 64;
  #pragma unroll
  for (int kk = 0; kk < 2; ++kk) {
    bf16x8 af = *(const bf16x8*)(&w1buf[wm + fr][kk * 32 + fk]);
    #pragma unroll
    for (int ni = 0; ni < 12; ++ni) {
      bf16x8 bv = *(const bf16x8*)(Mb + (size_t)(ni * 16 + fr) * 64 + kk * 32 + fk);
      acc2[ni] = __builtin_amdgcn_mfma_f32_16x16x32_bf16(af, bv, acc2[ni], 0, 0, 0);
    }
  }
  #pragma unroll
  for (int ni = 0; ni < 12; ++ni)
    #pragma unroll
    for (int r = 0; r < 4; ++r)
      out1[(size_t)(b * NNC + m0 + wm + row4 + r) * HH + ni * 16 + col16]
          = acc2[ni][r];
}

// ======== w2 softmax over n (normalized weights) ========
__global__ __launch_bounds__(256)
void k_w2(const float* __restrict__ rowmax, float* __restrict__ w2buf)
{
  const int b = blockIdx.x, t = threadIdx.x;
  __shared__ float red[256];
  const float* rm = rowmax + (size_t)b * NNC;
  float m = -1e30f;
  for (int n = t; n < NNC; n += 256) m = fmaxf(m, rm[n]);
  red[t] = m; __syncthreads();
  for (int s = 128; s; s >>= 1) { if (t < s) red[t] = fmaxf(red[t], red[t+s]); __syncthreads(); }
  m = red[0]; __syncthreads();
  float ssum = 0.f;
  for (int n = t; n < NNC; n += 256) { float e = expf(rm[n] - m); w2buf[b*NNC + n] = e; ssum += e; }
  red[t] = ssum; __syncthreads();
  for (int s = 128; s; s >>= 1) { if (t < s) red[t] += red[t+s]; __syncthreads(); }
  float inv = 1.f / red[0];
  for (int n = t; n < NNC; n += 256) w2buf[b*NNC + n] *= inv;
}

// ======== out2 partials ========
__global__ __launch_bounds__(192)
void k_out2p(const float* __restrict__ w2buf, const float* __restrict__ inp2,
             float* __restrict__ part)
{
  const int g = blockIdx.x, b = blockIdx.y, h = threadIdx.x;
  const float* w  = w2buf + (size_t)b * NNC + g * 128;
  const float* ip = inp2 + ((size_t)b * NNC + g * 128) * HH + h;
  float acc = 0.f;
  for (int n = 0; n < 128; ++n) acc += w[n] * ip[(size_t)n * HH];
  part[((size_t)b * 16 + g) * HH + h] = acc;
}
__global__ __launch_bounds__(192)
void k_out2r(const float* __restrict__ part, float* __restrict__ out2)
{
  const int b = blockIdx.x, h = threadIdx.x;
  float acc = 0.f;
  #pragma unroll
  for (int g = 0; g < 16; ++g) acc += part[((size_t)b * 16 + g) * HH + h];
  out2[b * HH + h] = acc;
}

// ======== merged logits: blocks [0,4096) concept, [4096,6496) triple ========
__global__ __launch_bounds__(256)
void k_logits(const unsigned short* __restrict__ cf_bf, const float* __restrict__ inp2,
              const float* __restrict__ out1, const float* __restrict__ out2,
              const float* __restrict__ c_query, const float* __restrict__ t_query,
              const int* __restrict__ head_idxs, const int* __restrict__ tail_idxs,
              const int* __restrict__ rel_ids, const float* __restrict__ rtab,
              float* __restrict__ out)
{
  __shared__ float tqs[3840];
  const int blk = blockIdx.x, lane = threadIdx.x & 63, w = threadIdx.x >> 6;
  if (blk < 4096) {
    const int bn = blk * 4 + w;
    const int b = bn >> 11, n = bn & 2047;
    const float* cq  = c_query + (size_t)b * 1536;
    const unsigned short* cfr = cf_bf + (size_t)bn * BD;
    const float* i2  = inp2 + (size_t)bn * HH;
    const float* o1  = out1 + (size_t)bn * HH;
    const float* o2  = out2 + (size_t)b * HH;
    float acc = 0.f;
    for (int d = lane; d < BD; d += 64) acc += bf2f(cfr[d]) * cq[d];
    #pragma unroll
    for (int j = 0; j < 3; ++j) {
      int h = lane + 64 * j;
      float a = i2[h], o = o1[h];
      acc += a * cq[768+h] + o * cq[960+h] + a*o * cq[1152+h] + o2[h]*o * cq[1344+h];
    }
    acc = wave_sum64(acc);
    if (lane == 0) out[(size_t)b * 3248 + n] = 1.f / (1.f + expf(-acc));
  } else {
    const int blk2 = blk - 4096;
    const int b = blk2 / 300;
    const int e = (blk2 % 300) * 4 + w;
    const float* tq = t_query + (size_t)b * 3840;
    for (int i = threadIdx.x; i < 3840; i += 256) tqs[i] = tq[i];
    __syncthreads();
    const int be = b * NNE + e;
    const int hi = head_idxs[be], ti = tail_idxs[be], rid = rel_ids[be];
    const unsigned short* ch = cf_bf + ((size_t)b * NNC + hi) * BD;
    const unsigned short* ct = cf_bf + ((size_t)b * NNC + ti) * BD;
    const float* rr = rtab + (size_t)rid * BD;
    const float* i2 = inp2 + ((size_t)b * NNC + hi) * HH;
    const float* o1 = out1 + ((size_t)b * NNC + hi) * HH;
    const float* o2 = out2 + (size_t)b * HH;
    float acc = 0.f;
    for (int d = lane; d < BD; d += 64) {
      float hd = bf2f(ch[d]), td = bf2f(ct[d]);
      acc += hd * tqs[d] + rr[d] * tqs[768+d] + td * tqs[1536+d] + hd*td * tqs[2304+d];
    }
    #pragma unroll
    for (int j = 0; j < 3; ++j) {
      int h = lane + 64 * j;
      float a = i2[h], o = o1[h];
      acc += a * tqs[3072+h] + o * tqs[3264+h] + a*o * tqs[3456+h] + o2[h]*o * tqs[3648+h];
    }
    acc = wave_sum64(acc);
    if (lane == 0) out[(size_t)b * 3248 + 2048 + e] = 1.f / (1.f + expf(-acc));
  }
}

extern "C" void kernel_launch(void* const* d_in, const int* in_sizes, int n_in,
                              void* d_out, int out_size, void* d_ws, size_t ws_size,
                              hipStream_t stream) {
  const float* qh        = (const float*)d_in[0];
  const int*   head_cids = (const int*)d_in[2];
  const int*   distances = (const int*)d_in[3];
  const int*   head_idxs = (const int*)d_in[4];
  const int*   tail_idxs = (const int*)d_in[5];
  const int*   rel_ids   = (const int*)d_in[6];
  const float* ctab      = (const float*)d_in[7];
  const float* dtab      = (const float*)d_in[8];
  const float* rtab      = (const float*)d_in[9];
  const float* W_ce      = (const float*)d_in[10];
  const float* b_ce      = (const float*)d_in[11];
  const float* W_cs      = (const float*)d_in[12];
  const float* b_cs      = (const float*)d_in[13];
  const float* W_ts      = (const float*)d_in[14];
  const float* b_ts      = (const float*)d_in[15];
  const float* w_in1     = (const float*)d_in[16];
  const float* w_mem1    = (const float*)d_in[17];
  const float* W_in2     = (const float*)d_in[18];
  const float* b_in2     = (const float*)d_in[19];
  const float* W_mem2    = (const float*)d_in[20];
  const float* b_mem2    = (const float*)d_in[21];
  float* out = (float*)d_out;

  // ---- workspace layout ----
  float* fp      = (float*)d_ws;
  float* c_query = fp;                    fp += 12288;
  float* t_query = fp;                    fp += 30720;
  float* mdot    = fp;                    fp += 512;
  float* rowmax  = fp;                    fp += 16384;
  float* w2buf   = fp;                    fp += 16384;
  float* part    = fp;                    fp += 24576;
  float* out2    = fp;                    fp += 1536;
  float* dcon    = fp;                    fp += 3072;     // [4][768]
  float* inp2    = fp;                    fp += 3145728;
  float* out1    = fp;                    fp += 3145728;
  unsigned short* cf_bf  = (unsigned short*)fp;
  unsigned short* Wce_t  = cf_bf  + 12582912ull;    // 768 x 800 (B^T augmented)
  unsigned short* Win2_t = Wce_t  + 614400ull;      // 192*768
  unsigned short* qhx    = Win2_t + 147456ull;      // 8*80*768
  unsigned short* mem2t  = qhx    + 491520ull;      // 8*192*64
  unsigned short* A_aug  = mem2t  + 98304ull;       // 16384 x 800

  // ---- conversions / precompute ----
  k_tcvt<<<dim3(BD/32, BD/32), 256, 0, stream>>>(W_ce, Wce_t, BD, BD, KAUG);
  k_tcvt<<<dim3(HH/32, BD/32), 256, 0, stream>>>(W_in2, Win2_t, BD, HH, BD);
  k_pre<<<dim3(NB, 25), 256, 0, stream>>>(qh, W_cs, b_cs, W_ts, b_ts, w_mem1,
                                          W_ce, b_ce, dtab,
                                          c_query, t_query, mdot, dcon);
  k_cvt_gather<<<(M_ROWS*100 + 24576)/256, 256, 0, stream>>>(
      head_cids, distances, ctab, dcon, A_aug, Wce_t);
  k_mem2qhx<<<(98304 + 491520)/256, 256, 0, stream>>>(qh, W_mem2, b_mem2, w_in1,
                                                      mem2t, qhx);

  // ---- MFMA GEMMs ----
  gemm_bt<128,128,true><<<dim3(M_ROWS/128, BD/128), 256, 0, stream>>>(
      A_aug, Wce_t, nullptr, nullptr, cf_bf, KAUG, BD);
  gemm_bt<128,64,false><<<dim3(M_ROWS/128, HH/64), 256, 0, stream>>>(
      cf_bf, Win2_t, b_in2, inp2, nullptr, BD, HH);

  // ---- fused attention ----
  k_attf<<<dim3(NNC/64, NB), 256, 0, stream>>>(cf_bf, qhx, mdot, mem2t, out1, rowmax);

  // ---- w2 / out2 / scoring ----
  k_w2<<<NB, 256, 0, stream>>>(rowmax, w2buf);
  k_out2p<<<dim3(16, NB), 192, 0, stream>>>(w2buf, inp2, part);
  k_out2r<<<NB, 192, 0, stream>>>(part, out2);
  k_logits<<<4096 + 2400, 256, 0, stream>>>(cf_bf, inp2, out1, out2, c_query, t_query,
                                            head_idxs, tail_idxs, rel_ids, rtab, out);
}

// Round 4
// 589.076 us; speedup vs baseline: 1.3340x; 1.1370x over previous
//
#include <hip/hip_runtime.h>
#include <hip/hip_bf16.h>
#include <math.h>

#define BD   768
#define HH   192
#define NB   8
#define NLQ  64
#define NNC  2048
#define NNE  1200
#define M_ROWS (NB*NNC)   // 16384
#define KAUG 800          // 768 + 32 (one-hot dist slots, zero-padded)

typedef float  f32x4  __attribute__((ext_vector_type(4)));
typedef short  bf16x8 __attribute__((ext_vector_type(8)));

__device__ __forceinline__ float wave_sum64(float v){
  #pragma unroll
  for (int off = 32; off; off >>= 1) v += __shfl_xor(v, off);
  return v;
}
__device__ __forceinline__ unsigned short f2bf(float f){
  union { float f; unsigned int u; } v; v.f = f;
  unsigned int u = v.u + 0x7fffu + ((v.u >> 16) & 1u);   // RNE
  return (unsigned short)(u >> 16);
}
__device__ __forceinline__ float bf2f(unsigned short h){
  union { unsigned int u; float f; } v; v.u = ((unsigned int)h) << 16; return v.f;
}
__device__ __forceinline__ unsigned int pack2(float lo, float hi){
  return ((unsigned int)f2bf(hi) << 16) | (unsigned int)f2bf(lo);
}

// ================== fused precompute: one launch, 5 independent ranges =====
// [0,200)       : pre  (c_query/t_query/mdot; chunks 22-24 write Wce_t dist cols)
// [200,6600)    : A_aug gather (ctab -> bf16 ++ one-hot(dist) ++ zeros)
// [6600,8904)   : mem2t + qhx conversion
// [8904,9480)   : tcvt W_ce -> Wce_t[768][800] cols 0..767
// [9480,9624)   : tcvt W_in2 -> Win2_t[192][768]
__global__ __launch_bounds__(256)
void k_prep(const float* __restrict__ qh,
            const int* __restrict__ cids, const int* __restrict__ dsts,
            const float* __restrict__ ctab, const float* __restrict__ dtab,
            const float* __restrict__ W_ce, const float* __restrict__ b_ce,
            const float* __restrict__ W_cs, const float* __restrict__ b_cs,
            const float* __restrict__ W_ts, const float* __restrict__ b_ts,
            const float* __restrict__ w_mem1, const float* __restrict__ W_in2,
            const float* __restrict__ W_mem2, const float* __restrict__ b_mem2,
            const float* __restrict__ w_in1,
            unsigned short* __restrict__ Wce_t, unsigned short* __restrict__ Win2_t,
            unsigned short* __restrict__ Aaug, unsigned short* __restrict__ qhx,
            unsigned short* __restrict__ mem2t,
            float* __restrict__ c_query, float* __restrict__ t_query,
            float* __restrict__ mdot)
{
  __shared__ float T[32][33];
  __shared__ float qe[BD];
  int blk = blockIdx.x;
  const int t = threadIdx.x;

  if (blk < 200) {                       // ---- pre ----
    const int b = blk & 7, chunk = blk >> 3;
    if (chunk >= 22) {                   // dist contribution -> Wce_t[c][768..800)
      if (b != 0) return;
      const int c = (chunk - 22) * 256 + t;     // < 768
      float a0 = b_ce[c], a1 = a0, a2 = a0, a3 = a0;
      for (int d = 0; d < BD; ++d) {
        float w = W_ce[(size_t)(BD + d) * BD + c];
        a0 += dtab[d]          * w;
        a1 += dtab[BD + d]     * w;
        a2 += dtab[2 * BD + d] * w;
        a3 += dtab[3 * BD + d] * w;
      }
      unsigned short* dst = Wce_t + (size_t)c * KAUG + BD;
      dst[0] = f2bf(a0); dst[1] = f2bf(a1); dst[2] = f2bf(a2); dst[3] = f2bf(a3);
      #pragma unroll
      for (int j = 4; j < 32; ++j) dst[j] = 0;
      return;
    }
    if (chunk == 21) {                   // mdot
      if (t < NLQ) {
        const float* q = qh + ((size_t)b * NLQ + t) * BD;
        float acc = 0.f;
        #pragma unroll 4
        for (int d = 0; d < BD; d += 4) {
          float4 v = *(const float4*)(q + d);
          acc += v.x*w_mem1[d] + v.y*w_mem1[d+1] + v.z*w_mem1[d+2] + v.w*w_mem1[d+3];
        }
        mdot[b * NLQ + t] = acc;
      }
      return;
    }
    for (int d = t; d < BD; d += 256) {  // q_emb maxpool into LDS
      const float* p = qh + (size_t)b * NLQ * BD + d;
      float m = -1e30f;
      for (int l = 0; l < NLQ; ++l) m = fmaxf(m, p[(size_t)l * BD]);
      qe[d] = m;
    }
    __syncthreads();
    int j = chunk * 256 + t;
    if (j < 1536) {
      float acc = b_cs[j];
      for (int d = 0; d < BD; ++d) acc += qe[d] * W_cs[(size_t)d * 1536 + j];
      c_query[b * 1536 + j] = acc;
    } else {
      int j2 = j - 1536;
      float acc = b_ts[j2];
      for (int d = 0; d < BD; ++d) acc += qe[d] * W_ts[(size_t)d * 3840 + j2];
      t_query[b * 3840 + j2] = acc;
    }
    return;
  }
  blk -= 200;

  if (blk < 6400) {                      // ---- A_aug gather ----
    int idx = blk * 256 + t;             // < 16384*100
    int row = idx / 100, kc = idx - row * 100;
    unsigned short* dst = Aaug + (size_t)row * KAUG + kc * 8;
    if (kc < 96) {
      int cid = cids[row];
      const float* src = ctab + (size_t)cid * BD + kc * 8;
      float4 f0 = ((const float4*)src)[0];
      float4 f1 = ((const float4*)src)[1];
      uint4 o;
      o.x = pack2(f0.x, f0.y); o.y = pack2(f0.z, f0.w);
      o.z = pack2(f1.x, f1.y); o.w = pack2(f1.z, f1.w);
      *(uint4*)dst = o;
    } else if (kc == 96) {
      int d = dsts[row];                 // 0..3
      uint4 o;
      o.x = (d == 0 ? 0x3F80u : 0u) | (d == 1 ? 0x3F800000u : 0u);
      o.y = (d == 2 ? 0x3F80u : 0u) | (d == 3 ? 0x3F800000u : 0u);
      o.z = 0u; o.w = 0u;
      *(uint4*)dst = o;
    } else {
      uint4 z = {0u, 0u, 0u, 0u};
      *(uint4*)dst = z;
    }
    return;
  }
  blk -= 6400;

  if (blk < 2304) {                      // ---- mem2t + qhx ----
    int idx = blk * 256 + t;             // < 98304 + 491520
    if (idx < 98304) {
      int h = idx % HH, bl = idx / HH;   // bl = b*64 + l
      int b = bl >> 6, l = bl & 63;
      const float* q = qh + (size_t)bl * BD;
      float acc = b_mem2[h];
      for (int d = 0; d < BD; ++d) acc += q[d] * W_mem2[(size_t)d * HH + h];
      mem2t[((size_t)b * HH + h) * 64 + l] = f2bf(acc);
    } else {
      int i = idx - 98304;
      int b = i / 61440, rk = i - b * 61440;
      int r = rk / BD, k = rk - r * BD;
      unsigned short v;
      if (r < 64)       v = f2bf(qh[((size_t)b * NLQ + r) * BD + k]);
      else if (r == 64) v = f2bf(w_in1[k] * 27.712812921102035f);  // sqrt(768)
      else              v = 0;
      qhx[i] = v;
    }
    return;
  }
  blk -= 2304;

  if (blk < 576) {                       // ---- tcvt W_ce -> Wce_t ----
    const int bx = blk % 24, by = blk / 24;
    const int tx = t & 31, ty = t >> 5;
    const int c0 = bx * 32, r0 = by * 32;
    #pragma unroll
    for (int i = 0; i < 4; ++i)
      T[ty + i * 8][tx] = W_ce[(size_t)(r0 + ty + i * 8) * BD + c0 + tx];
    __syncthreads();
    #pragma unroll
    for (int i = 0; i < 4; ++i)
      Wce_t[(size_t)(c0 + ty + i * 8) * KAUG + r0 + tx] = f2bf(T[tx][ty + i * 8]);
    return;
  }
  blk -= 576;

  {                                      // ---- tcvt W_in2 -> Win2_t ----
    const int bx = blk % 6, by = blk / 6;
    const int tx = t & 31, ty = t >> 5;
    const int c0 = bx * 32, r0 = by * 32;
    #pragma unroll
    for (int i = 0; i < 4; ++i)
      T[ty + i * 8][tx] = W_in2[(size_t)(r0 + ty + i * 8) * HH + c0 + tx];
    __syncthreads();
    #pragma unroll
    for (int i = 0; i < 4; ++i)
      Win2_t[(size_t)(c0 + ty + i * 8) * BD + r0 + tx] = f2bf(T[tx][ty + i * 8]);
  }
}

// ======== m97-style bf16 MFMA GEMM, B^T layout ========
template<int BM, int BN, bool BF16OUT>
__global__ __launch_bounds__(256)
void gemm_bt(const unsigned short* __restrict__ A,
             const unsigned short* __restrict__ Bt,
             const float* __restrict__ bias,
             float* __restrict__ Cf, unsigned short* __restrict__ Cb,
             int K, int N)
{
  constexpr int BK = 32;
  __shared__ unsigned short As[BM * BK];
  __shared__ unsigned short Bs[BN * BK];
  const int tid = threadIdx.x;
  const int lane = tid & 63, wave = tid >> 6;
  const int m0 = blockIdx.x * BM, n0 = blockIdx.y * BN;
  const int wm = (wave & 1) * (BM / 2);
  const int wn = (wave >> 1) * (BN / 2);
  constexpr int FM = BM / 32, FN = BN / 32;
  constexpr int CA = (BM * 4) / 256, CB = (BN * 4) / 256;

  f32x4 acc[FM][FN] = {};
  const int fr = lane & 15;
  const int fk = (lane >> 4) * 8;

  for (int k0 = 0; k0 < K; k0 += BK) {
    __syncthreads();
    #pragma unroll
    for (int i = 0; i < CA; ++i) {
      int c = i * 256 + tid;
      const unsigned short* g = A + (size_t)(m0 + (c >> 2)) * K + k0 + (c & 3) * 8;
      __builtin_amdgcn_global_load_lds(
          (const __attribute__((address_space(1))) void*)g,
          (__attribute__((address_space(3))) void*)(As + c * 8), 16, 0, 0);
    }
    #pragma unroll
    for (int i = 0; i < CB; ++i) {
      int c = i * 256 + tid;
      const unsigned short* g = Bt + (size_t)(n0 + (c >> 2)) * K + k0 + (c & 3) * 8;
      __builtin_amdgcn_global_load_lds(
          (const __attribute__((address_space(1))) void*)g,
          (__attribute__((address_space(3))) void*)(Bs + c * 8), 16, 0, 0);
    }
    __syncthreads();
    bf16x8 af[FM], bfv[FN];
    #pragma unroll
    for (int mi = 0; mi < FM; ++mi)
      af[mi] = *(const bf16x8*)(As + (wm + mi * 16 + fr) * BK + fk);
    #pragma unroll
    for (int ni = 0; ni < FN; ++ni)
      bfv[ni] = *(const bf16x8*)(Bs + (wn + ni * 16 + fr) * BK + fk);
    #pragma unroll
    for (int mi = 0; mi < FM; ++mi)
      #pragma unroll
      for (int ni = 0; ni < FN; ++ni)
        acc[mi][ni] = __builtin_amdgcn_mfma_f32_16x16x32_bf16(
            af[mi], bfv[ni], acc[mi][ni], 0, 0, 0);
  }

  const int col16 = lane & 15, row4 = (lane >> 4) * 4;
  #pragma unroll
  for (int mi = 0; mi < FM; ++mi) {
    #pragma unroll
    for (int ni = 0; ni < FN; ++ni) {
      int col = n0 + wn + ni * 16 + col16;
      float bv = bias ? bias[col] : 0.0f;
      int rowb = m0 + wm + mi * 16 + row4;
      #pragma unroll
      for (int r = 0; r < 4; ++r) {
        float v = acc[mi][ni][r] + bv;
        size_t off = (size_t)(rowb + r) * N + col;
        if (BF16OUT) Cb[off] = f2bf(v);
        else         Cf[off] = v;
      }
    }
  }
}

// ======== fused attention + inp2 GEMM: QK^T & cf@W_in2 share the cf K-loop;
//          parallel softmax; PV via MFMA; per-tile max for w2 ========
__global__ __launch_bounds__(256)
void k_attf(const unsigned short* __restrict__ cf_bf,
            const unsigned short* __restrict__ qhx,
            const float* __restrict__ mdot,
            const unsigned short* __restrict__ mem2t,
            const unsigned short* __restrict__ win2t,
            const float* __restrict__ b_in2,
            float* __restrict__ out1, float* __restrict__ inp2,
            float* __restrict__ rowmax, float* __restrict__ tmax)
{
  __shared__ unsigned short As[64 * 32];
  __shared__ unsigned short Bs[80 * 32];
  __shared__ unsigned short Bs2[192 * 32];
  __shared__ float Sbuf[64][81];
  __shared__ unsigned short w1buf[64][72];
  __shared__ float mds[64];
  __shared__ float wred[4];
  const int tid = threadIdx.x, lane = tid & 63, wave = tid >> 6;
  const int m0 = blockIdx.x * 64, b = blockIdx.y;
  if (tid < 64) mds[tid] = mdot[b * NLQ + tid];
  const unsigned short* Ab = cf_bf + ((size_t)b * NNC + m0) * BD;
  const unsigned short* Bb = qhx + (size_t)b * 80 * BD;
  const int fr = lane & 15, fk = (lane >> 4) * 8;
  const int wm = wave * 16;
  f32x4 acc[5] = {};
  f32x4 accI[12] = {};

  for (int k0 = 0; k0 < BD; k0 += 32) {
    __syncthreads();
    {
      int c = tid;   // A: 64 rows x 4 chunks = 256
      const unsigned short* g = Ab + (size_t)(c >> 2) * BD + k0 + (c & 3) * 8;
      __builtin_amdgcn_global_load_lds(
          (const __attribute__((address_space(1))) void*)g,
          (__attribute__((address_space(3))) void*)(As + c * 8), 16, 0, 0);
    }
    {
      int c = tid;   // B: 80 rows x 4 chunks = 320
      const unsigned short* g = Bb + (size_t)(c >> 2) * BD + k0 + (c & 3) * 8;
      __builtin_amdgcn_global_load_lds(
          (const __attribute__((address_space(1))) void*)g,
          (__attribute__((address_space(3))) void*)(Bs + c * 8), 16, 0, 0);
      if (tid < 64) {
        c = 256 + tid;
        g = Bb + (size_t)(c >> 2) * BD + k0 + (c & 3) * 8;
        __builtin_amdgcn_global_load_lds(
            (const __attribute__((address_space(1))) void*)g,
            (__attribute__((address_space(3))) void*)(Bs + c * 8), 16, 0, 0);
      }
    }
    #pragma unroll
    for (int i = 0; i < 3; ++i) {        // W_in2: 192 rows x 4 chunks = 768
      int c = i * 256 + tid;
      const unsigned short* g = win2t + (size_t)(c >> 2) * BD + k0 + (c & 3) * 8;
      __builtin_amdgcn_global_load_lds(
          (const __attribute__((address_space(1))) void*)g,
          (__attribute__((address_space(3))) void*)(Bs2 + c * 8), 16, 0, 0);
    }
    __syncthreads();
    bf16x8 af = *(const bf16x8*)(As + (wm + fr) * 32 + fk);
    #pragma unroll
    for (int ni = 0; ni < 5; ++ni) {
      bf16x8 bv = *(const bf16x8*)(Bs + (ni * 16 + fr) * 32 + fk);
      acc[ni] = __builtin_amdgcn_mfma_f32_16x16x32_bf16(af, bv, acc[ni], 0, 0, 0);
    }
    #pragma unroll
    for (int ni = 0; ni < 12; ++ni) {
      bf16x8 bv = *(const bf16x8*)(Bs2 + (ni * 16 + fr) * 32 + fk);
      accI[ni] = __builtin_amdgcn_mfma_f32_16x16x32_bf16(af, bv, accI[ni], 0, 0, 0);
    }
  }
  const int col16 = lane & 15, row4 = (lane >> 4) * 4;
  // inp2 epilogue (releases accI)
  #pragma unroll
  for (int ni = 0; ni < 12; ++ni) {
    float bv = b_in2[ni * 16 + col16];
    #pragma unroll
    for (int r = 0; r < 4; ++r)
      inp2[(size_t)(b * NNC + m0 + wm + row4 + r) * HH + ni * 16 + col16]
          = accI[ni][r] + bv;
  }
  #pragma unroll
  for (int ni = 0; ni < 5; ++ni)
    #pragma unroll
    for (int r = 0; r < 4; ++r)
      Sbuf[wm + row4 + r][ni * 16 + col16] = acc[ni][r];
  __syncthreads();

  // softmax: each wave its own 16 rows; 4 lanes per row, 16 l each
  {
    const float scale = 0.03608439182435161f;    // 1/sqrt(768)
    const int r = wm + (lane >> 2);
    const int q = lane & 3;
    float e[16];
    float mx = -1e30f;
    #pragma unroll
    for (int i = 0; i < 16; ++i) {
      int l = q * 16 + i;
      float v = mds[l] + Sbuf[r][l] * scale;
      e[i] = v; mx = fmaxf(mx, v);
    }
    mx = fmaxf(mx, __shfl_xor(mx, 1));
    mx = fmaxf(mx, __shfl_xor(mx, 2));
    float s = 0.f;
    #pragma unroll
    for (int i = 0; i < 16; ++i) { e[i] = expf(e[i] - mx); s += e[i]; }
    s += __shfl_xor(s, 1);
    s += __shfl_xor(s, 2);
    float inv = 1.f / s;
    float rv = mx + Sbuf[r][64] * scale;         // rowmax incl. input_dot
    if (q == 0) rowmax[b * NNC + m0 + r] = rv;
    #pragma unroll
    for (int off = 32; off; off >>= 1) rv = fmaxf(rv, __shfl_xor(rv, off));
    if (lane == 0) wred[wave] = rv;
    #pragma unroll
    for (int i = 0; i < 16; ++i) w1buf[r][q * 16 + i] = f2bf(e[i] * inv);
  }
  __syncthreads();
  if (tid == 0)
    tmax[b * 32 + blockIdx.x] =
        fmaxf(fmaxf(wred[0], wred[1]), fmaxf(wred[2], wred[3]));

  // PV: out1[64,192] = w1[64,64] @ mem2t[192,64]^T
  f32x4 acc2[12] = {};
  const unsigned short* Mb = mem2t + (size_t)b * HH * 64;
  #pragma unroll
  for (int kk = 0; kk < 2; ++kk) {
    bf16x8 af = *(const bf16x8*)(&w1buf[wm + fr][kk * 32 + fk]);
    #pragma unroll
    for (int ni = 0; ni < 12; ++ni) {
      bf16x8 bv = *(const bf16x8*)(Mb + (size_t)(ni * 16 + fr) * 64 + kk * 32 + fk);
      acc2[ni] = __builtin_amdgcn_mfma_f32_16x16x32_bf16(af, bv, acc2[ni], 0, 0, 0);
    }
  }
  #pragma unroll
  for (int ni = 0; ni < 12; ++ni)
    #pragma unroll
    for (int r = 0; r < 4; ++r)
      out1[(size_t)(b * NNC + m0 + wm + row4 + r) * HH + ni * 16 + col16]
          = acc2[ni][r];
}

// ======== out2 partials with inline w2 (unnormalized exp) ========
__global__ __launch_bounds__(192)
void k_out2p(const float* __restrict__ rowmax, const float* __restrict__ tmax,
             const float* __restrict__ inp2,
             float* __restrict__ part_num, float* __restrict__ part_den)
{
  const int g = blockIdx.x, b = blockIdx.y, h = threadIdx.x;
  float m = -1e30f;
  #pragma unroll
  for (int i = 0; i < 32; ++i) m = fmaxf(m, tmax[b * 32 + i]);
  const float* rm = rowmax + (size_t)b * NNC + g * 128;
  const float* ip = inp2 + ((size_t)b * NNC + g * 128) * HH + h;
  float num = 0.f, den = 0.f;
  for (int n = 0; n < 128; ++n) {
    float e = expf(rm[n] - m);
    num += e * ip[(size_t)n * HH];
    den += e;
  }
  part_num[((size_t)b * 16 + g) * HH + h] = num;
  if (h == 0) part_den[b * 16 + g] = den;
}

// ======== merged logits (reconstructs out2 from partials in LDS) ========
__global__ __launch_bounds__(256)
void k_logits(const unsigned short* __restrict__ cf_bf, const float* __restrict__ inp2,
              const float* __restrict__ out1,
              const float* __restrict__ part_num, const float* __restrict__ part_den,
              const float* __restrict__ c_query, const float* __restrict__ t_query,
              const int* __restrict__ head_idxs, const int* __restrict__ tail_idxs,
              const int* __restrict__ rel_ids, const float* __restrict__ rtab,
              float* __restrict__ out)
{
  __shared__ float tqs[3840];
  __shared__ float o2s[HH];
  const int blk = blockIdx.x, lane = threadIdx.x & 63, w = threadIdx.x >> 6;
  const bool concept = blk < 4096;
  const int b = concept ? (blk >> 9) : ((blk - 4096) / 300);

  if (threadIdx.x < HH) {
    float den = 0.f, num = 0.f;
    #pragma unroll
    for (int g = 0; g < 16; ++g) {
      den += part_den[b * 16 + g];
      num += part_num[(size_t)(b * 16 + g) * HH + threadIdx.x];
    }
    o2s[threadIdx.x] = num / den;
  }
  if (!concept) {
    const float* tq = t_query + (size_t)b * 3840;
    for (int i = threadIdx.x; i < 3840; i += 256) tqs[i] = tq[i];
  }
  __syncthreads();

  if (concept) {
    const int bn = blk * 4 + w;
    const int n = bn & 2047;
    const float* cq  = c_query + (size_t)b * 1536;
    const unsigned short* cfr = cf_bf + (size_t)bn * BD;
    const float* i2  = inp2 + (size_t)bn * HH;
    const float* o1  = out1 + (size_t)bn * HH;
    float acc = 0.f;
    for (int d = lane; d < BD; d += 64) acc += bf2f(cfr[d]) * cq[d];
    #pragma unroll
    for (int j = 0; j < 3; ++j) {
      int h = lane + 64 * j;
      float a = i2[h], o = o1[h];
      acc += a * cq[768+h] + o * cq[960+h] + a*o * cq[1152+h] + o2s[h]*o * cq[1344+h];
    }
    acc = wave_sum64(acc);
    if (lane == 0) out[(size_t)b * 3248 + n] = 1.f / (1.f + expf(-acc));
  } else {
    const int blk2 = blk - 4096;
    const int e = (blk2 % 300) * 4 + w;
    const int be = b * NNE + e;
    const int hi = head_idxs[be], ti = tail_idxs[be], rid = rel_ids[be];
    const unsigned short* ch = cf_bf + ((size_t)b * NNC + hi) * BD;
    const unsigned short* ct = cf_bf + ((size_t)b * NNC + ti) * BD;
    const float* rr = rtab + (size_t)rid * BD;
    const float* i2 = inp2 + ((size_t)b * NNC + hi) * HH;
    const float* o1 = out1 + ((size_t)b * NNC + hi) * HH;
    float acc = 0.f;
    for (int d = lane; d < BD; d += 64) {
      float hd = bf2f(ch[d]), td = bf2f(ct[d]);
      acc += hd * tqs[d] + rr[d] * tqs[768+d] + td * tqs[1536+d] + hd*td * tqs[2304+d];
    }
    #pragma unroll
    for (int j = 0; j < 3; ++j) {
      int h = lane + 64 * j;
      float a = i2[h], o = o1[h];
      acc += a * tqs[3072+h] + o * tqs[3264+h] + a*o * tqs[3456+h] + o2s[h]*o * tqs[3648+h];
    }
    acc = wave_sum64(acc);
    if (lane == 0) out[(size_t)b * 3248 + 2048 + e] = 1.f / (1.f + expf(-acc));
  }
}

extern "C" void kernel_launch(void* const* d_in, const int* in_sizes, int n_in,
                              void* d_out, int out_size, void* d_ws, size_t ws_size,
                              hipStream_t stream) {
  const float* qh        = (const float*)d_in[0];
  const int*   head_cids = (const int*)d_in[2];
  const int*   distances = (const int*)d_in[3];
  const int*   head_idxs = (const int*)d_in[4];
  const int*   tail_idxs = (const int*)d_in[5];
  const int*   rel_ids   = (const int*)d_in[6];
  const float* ctab      = (const float*)d_in[7];
  const float* dtab      = (const float*)d_in[8];
  const float* rtab      = (const float*)d_in[9];
  const float* W_ce      = (const float*)d_in[10];
  const float* b_ce      = (const float*)d_in[11];
  const float* W_cs      = (const float*)d_in[12];
  const float* b_cs      = (const float*)d_in[13];
  const float* W_ts      = (const float*)d_in[14];
  const float* b_ts      = (const float*)d_in[15];
  const float* w_in1     = (const float*)d_in[16];
  const float* w_mem1    = (const float*)d_in[17];
  const float* W_in2     = (const float*)d_in[18];
  const float* b_in2     = (const float*)d_in[19];
  const float* W_mem2    = (const float*)d_in[20];
  const float* b_mem2    = (const float*)d_in[21];
  float* out = (float*)d_out;

  // ---- workspace layout ----
  float* fp       = (float*)d_ws;
  float* c_query  = fp;                   fp += 12288;
  float* t_query  = fp;                   fp += 30720;
  float* mdot     = fp;                   fp += 512;
  float* rowmax   = fp;                   fp += 16384;
  float* tmax     = fp;                   fp += 256;     // [8][32]
  float* part_num = fp;                   fp += 24576;   // [8][16][192]
  float* part_den = fp;                   fp += 128;     // [8][16]
  float* inp2     = fp;                   fp += 3145728;
  float* out1     = fp;                   fp += 3145728;
  unsigned short* cf_bf  = (unsigned short*)fp;
  unsigned short* Wce_t  = cf_bf  + 12582912ull;    // 768 x 800 (B^T augmented)
  unsigned short* Win2_t = Wce_t  + 614400ull;      // 192 x 768
  unsigned short* qhx    = Win2_t + 147456ull;      // 8*80*768
  unsigned short* mem2t  = qhx    + 491520ull;      // 8*192*64
  unsigned short* A_aug  = mem2t  + 98304ull;       // 16384 x 800

  // ---- 1: fused precompute ----
  k_prep<<<9624, 256, 0, stream>>>(qh, head_cids, distances, ctab, dtab,
                                   W_ce, b_ce, W_cs, b_cs, W_ts, b_ts,
                                   w_mem1, W_in2, W_mem2, b_mem2, w_in1,
                                   Wce_t, Win2_t, A_aug, qhx, mem2t,
                                   c_query, t_query, mdot);

  // ---- 2: concept-encoder GEMM ----
  gemm_bt<128,128,true><<<dim3(M_ROWS/128, BD/128), 256, 0, stream>>>(
      A_aug, Wce_t, nullptr, nullptr, cf_bf, KAUG, BD);

  // ---- 3: fused attention + inp2 ----
  k_attf<<<dim3(NNC/64, NB), 256, 0, stream>>>(cf_bf, qhx, mdot, mem2t,
                                               Win2_t, b_in2,
                                               out1, inp2, rowmax, tmax);

  // ---- 4: w2+out2 partials ----
  k_out2p<<<dim3(16, NB), 192, 0, stream>>>(rowmax, tmax, inp2, part_num, part_den);

  // ---- 5: logits ----
  k_logits<<<4096 + 2400, 256, 0, stream>>>(cf_bf, inp2, out1, part_num, part_den,
                                            c_query, t_query,
                                            head_idxs, tail_idxs, rel_ids, rtab, out);
}